// Round 10
// baseline (389.335 us; speedup 1.0000x reference)
//
#include <hip/hip_runtime.h>
#include <math.h>

typedef __attribute__((ext_vector_type(8))) short short8;
typedef __attribute__((ext_vector_type(4))) float f32x4;

#define CAPB 4096   // fixed capacity per coarse bucket (mean 2558, 30 sigma)

static __device__ __forceinline__ unsigned short f2bf(float f) {
  union { float f; unsigned int u; } x; x.f = f;
  unsigned int r = x.u + 0x7fffu + ((x.u >> 16) & 1u);  // RNE
  return (unsigned short)(r >> 16);
}
static __device__ __forceinline__ float bf2f(unsigned int u) {
  union { unsigned int u; float f; } x; x.u = u << 16; return x.f;
}

// ---------------------------------------------------------------------------
// Block 0: int64-vs-int32 edge_index detection. Block 1: zero gcursor[512].
__global__ void k_flag(const unsigned int* __restrict__ w, int nSample,
                       unsigned int* __restrict__ flag,
                       int* __restrict__ gcursor) {
  if (blockIdx.x == 1) {
    if (threadIdx.x < 256) { gcursor[threadIdx.x] = 0; gcursor[threadIdx.x + 256] = 0; }
    return;
  }
  if (blockIdx.x != 0) return;
  __shared__ unsigned int red[256];
  unsigned int v = 0;
  for (int i = threadIdx.x; i < nSample; i += 256) v |= w[2 * i + 1];
  red[threadIdx.x] = v;
  __syncthreads();
  for (int s = 128; s > 0; s >>= 1) {
    if (threadIdx.x < s) red[threadIdx.x] |= red[threadIdx.x + s];
    __syncthreads();
  }
  if (threadIdx.x == 0) flag[0] = red[0];  // nonzero => int32 layout
}

// ---------------------------------------------------------------------------
// MFMA node GEMM body. INLINEW: build B fragments directly from f32 W0/W1.
// MFMA layouts (gfx950, verified): A[m=lane&15][k=(lane>>4)*8+j],
// B[k][n=lane&15], C/D col=lane&15, row=(lane>>4)*4+reg.
template <int K, bool BF16IN, int NTILES, bool INLINEW>
__device__ __forceinline__ void ngemm_body(
    const void* __restrict__ Xv, const unsigned short* __restrict__ WnT,
    const float* __restrict__ W0f, const float* __restrict__ W1f,
    unsigned short* __restrict__ Y0, unsigned short* __restrict__ Y1,
    int N, int blk, unsigned short* __restrict__ sX) {
  constexpr int STR = K + 8;
  constexpr int NC = K / 32;
  const int tid = threadIdx.x;
  const int wv = tid >> 6, lane = tid & 63;
  const int m = lane & 15, q = lane >> 4;
  const int row0 = blk * 64;

  short8 bB[NTILES][NC];
#pragma unroll
  for (int ct = 0; ct < NTILES; ++ct)
#pragma unroll
    for (int c = 0; c < NC; ++c) {
      if constexpr (INLINEW) {
        int n = (NTILES == 2) ? (wv * 32 + ct * 16 + m) : (wv * 16 + m);
        const float* Wf = (n < 64) ? W0f : W1f;
        int nn = n & 63;
        union { short8 s; unsigned short h[8]; } ub;
#pragma unroll
        for (int j = 0; j < 8; ++j)
          ub.h[j] = f2bf(Wf[(size_t)(c * 32 + q * 8 + j) * 64 + nn]);
        bB[ct][c] = ub.s;
      } else {
        int n = (NTILES == 2) ? (wv * 32 + ct * 16 + m) : (wv * 16 + m);
        bB[ct][c] = *(const short8*)(WnT + (size_t)n * K + c * 32 + q * 8);
      }
    }

#pragma unroll
  for (int i = 0; i < K / 16; ++i) {
    int f = tid + 256 * i;
    int r = f / (K / 4);
    int c4 = f % (K / 4);
    int rr = row0 + r; if (rr >= N) rr = N - 1;
    uint2 pk;
    if constexpr (BF16IN) {
      pk = *(const uint2*)((const unsigned short*)Xv + (size_t)rr * K + c4 * 4);
    } else {
      float4 v = *(const float4*)((const float*)Xv + (size_t)rr * K + c4 * 4);
      pk.x = (unsigned int)f2bf(v.x) | ((unsigned int)f2bf(v.y) << 16);
      pk.y = (unsigned int)f2bf(v.z) | ((unsigned int)f2bf(v.w) << 16);
    }
    *(uint2*)(sX + r * STR + c4 * 4) = pk;
  }
  __syncthreads();

  f32x4 acc[4][NTILES];
#pragma unroll
  for (int rt = 0; rt < 4; ++rt)
#pragma unroll
    for (int ct = 0; ct < NTILES; ++ct)
#pragma unroll
      for (int r = 0; r < 4; ++r) acc[rt][ct][r] = 0.f;

#pragma unroll
  for (int c = 0; c < NC; ++c) {
    short8 a[4];
#pragma unroll
    for (int rt = 0; rt < 4; ++rt)
      a[rt] = *(const short8*)(sX + (rt * 16 + m) * STR + c * 32 + q * 8);
#pragma unroll
    for (int rt = 0; rt < 4; ++rt)
#pragma unroll
      for (int ct = 0; ct < NTILES; ++ct)
        acc[rt][ct] = __builtin_amdgcn_mfma_f32_16x16x32_bf16(a[rt], bB[ct][c], acc[rt][ct], 0, 0, 0);
  }

#pragma unroll
  for (int rt = 0; rt < 4; ++rt)
#pragma unroll
    for (int ct = 0; ct < NTILES; ++ct) {
      unsigned short* Yw;
      int n;
      if constexpr (NTILES == 2) {
        Yw = (wv < 2) ? Y0 : Y1;
        n = (wv & 1) * 32 + ct * 16 + m;
      } else {
        Yw = Y0;
        n = wv * 16 + m;
      }
#pragma unroll
      for (int reg = 0; reg < 4; ++reg) {
        int row = row0 + rt * 16 + q * 4 + reg;
        if (row < N) Yw[(size_t)row * 64 + n] = f2bf(acc[rt][ct][reg]);
      }
    }
}

// ---------------------------------------------------------------------------
// MEGA1: decode+bucket-scatter + prep + WnL2T + layer-0 GEMM (INLINEW).
// Proportional striping so decode blocks co-reside with compute from t=0.
__global__ __launch_bounds__(256) void k_mega1(
    const unsigned int* __restrict__ w, const unsigned int* __restrict__ flag,
    int E, int nDec, int nWork, int gB,
    int* __restrict__ src, int* __restrict__ tgt,
    int* __restrict__ gcursor, unsigned int* __restrict__ tmp,
    const float* __restrict__ x, unsigned short* __restrict__ Yl,
    unsigned short* __restrict__ Yr, int N,
    const float* __restrict__ We2, const float* __restrict__ Wo1,
    const float* __restrict__ be2, const float* __restrict__ bo1,
    const float* __restrict__ We1,
    const float* __restrict__ Wl0, const float* __restrict__ Wr0,
    const float* __restrict__ Wl1, const float* __restrict__ Wr1,
    unsigned short* __restrict__ W25T, unsigned short* __restrict__ We1T,
    unsigned short* __restrict__ Wo1T, float* __restrict__ cvec,
    unsigned short* __restrict__ WnL2T) {
  __shared__ __align__(16) char smem[64 * 136 * 2];   // 17408 B, union use
  const int tid = threadIdx.x;
  const int tot = nDec + nWork;
  const int di  = (int)(((long long)blockIdx.x * nDec) / tot);
  const int di1 = (int)(((long long)(blockIdx.x + 1) * nDec) / tot);

  if (di1 > di) {
    // ---- decode+scatter block #di: edges [di*4096, min(E, +4096))
    int* hist = (int*)smem;   // 512 ints
    hist[tid] = 0; hist[tid + 256] = 0;
    __syncthreads();
    const int e0 = di * 4096;
    const int e1 = (e0 + 4096 < E) ? (e0 + 4096) : E;
    const unsigned int fl = flag[0];
    for (int e = e0 + tid; e < e1; e += 256) {
      int s, t;
      if (fl) { s = (int)w[e]; t = (int)w[E + e]; }
      else    { s = (int)w[2 * e]; t = (int)w[2 * (E + e)]; }
      src[e] = s; tgt[e] = t;
      atomicAdd(hist + (t >> 8), 1);
    }
    __syncthreads();
    {
      int c0 = hist[tid], c1 = hist[tid + 256];
      int s0 = (c0 > 0) ? atomicAdd(gcursor + tid, c0) : 0;
      int s1 = (c1 > 0) ? atomicAdd(gcursor + tid + 256, c1) : 0;
      __syncthreads();
      hist[tid] = s0; hist[tid + 256] = s1;
    }
    __syncthreads();
    for (int e = e0 + tid; e < e1; e += 256) {
      int s, t;
      if (fl) { s = (int)w[e]; t = (int)w[E + e]; }
      else    { s = (int)w[2 * e]; t = (int)w[2 * (E + e)]; }
      int b = t >> 8;
      int pos = atomicAdd(hist + b, 1);
      if (pos < CAPB)
        tmp[(size_t)b * CAPB + pos] = ((unsigned int)s << 8) | (unsigned int)(t & 255);
    }
    return;
  }
  const int wi = blockIdx.x - di;
  if (wi == 0) {
    // ---- prep: W25T=(We2@Wo1)^T, Wo1T, We1T, cvec (Wo1 staged in smem)
    float* sB = (float*)smem;
    for (int i = tid; i < 1024; i += 256)
      *(float4*)&sB[i * 4] = *(const float4*)(Wo1 + i * 4);
    __syncthreads();
    for (int idx = tid; idx < 4096; idx += 256) {
      int k = idx >> 6, n = idx & 63;   // k wave-uniform -> We2 scalarizes
      float s = 0.f;
#pragma unroll 8
      for (int mm = 0; mm < 64; ++mm) s = fmaf(We2[k * 64 + mm], sB[mm * 64 + n], s);
      W25T[n * 64 + k] = f2bf(s);
      Wo1T[n * 64 + k] = f2bf(sB[k * 64 + n]);
    }
    for (int idx = tid; idx < 2048; idx += 256) {
      int n = idx >> 5, k = idx & 31;
      We1T[n * 32 + k] = (k < 16) ? f2bf(We1[k * 64 + n]) : (unsigned short)0;
    }
    if (tid < 64) {
      float s = bo1[tid];
#pragma unroll 8
      for (int mm = 0; mm < 64; ++mm) s = fmaf(be2[mm], sB[mm * 64 + tid], s);
      cvec[tid] = s;
    }
  } else if (wi <= 32) {
    // ---- WnL2T: [64 n][128 k], k<64 from Wl1, k>=64 from Wr1 (stacked K)
    int idx = (wi - 1) * 256 + tid;   // 0..8191
    int n = idx >> 7, k = idx & 127;
    float v = (k < 64) ? Wl1[(size_t)k * 64 + n]
                       : Wr1[(size_t)(k - 64) * 64 + n];
    WnL2T[idx] = f2bf(v);
  } else {
    // ---- layer-0 GEMM (inline f32 weights)
    ngemm_body<128, false, 2, true>(x, nullptr, Wl0, Wr0, Yl, Yr, N,
                                    wi - 33, (unsigned short*)smem);
  }
}

// ---------------------------------------------------------------------------
// Per-bucket counting sort + co-dispatched eattr conv (r8 form).
__global__ __launch_bounds__(256) void k_bsort(
    const unsigned int* __restrict__ tmp, const int* __restrict__ gcursor,
    int* __restrict__ csrc, uint2* __restrict__ rowptr2, int N, int nBuck,
    const float4* __restrict__ ef, uint2* __restrict__ eb, int nItems) {
  __shared__ int cnt[256];
  __shared__ int curs[256];
  __shared__ int wsum[4];
  const int tid = threadIdx.x;
  if (blockIdx.x >= nBuck) {
    const int ci = blockIdx.x - nBuck;
#pragma unroll
    for (int j = 0; j < 4; ++j) {
      int i = ci * 1024 + j * 256 + tid;
      if (i < nItems) {
        float4 v = ef[i];
        uint2 pk;
        pk.x = (unsigned int)f2bf(v.x) | ((unsigned int)f2bf(v.y) << 16);
        pk.y = (unsigned int)f2bf(v.z) | ((unsigned int)f2bf(v.w) << 16);
        eb[i] = pk;
      }
    }
    return;
  }
  const int b = blockIdx.x;
  int c = gcursor[b]; if (c > CAPB) c = CAPB;
  cnt[tid] = 0;
  __syncthreads();
  const unsigned int* reg = tmp + (size_t)b * CAPB;
  for (int i = tid; i < c; i += 256) atomicAdd(&cnt[reg[i] & 255u], 1);
  __syncthreads();
  const int lane = tid & 63, wv = tid >> 6;
  int v = cnt[tid];
  int incl = v;
#pragma unroll
  for (int off = 1; off < 64; off <<= 1) {
    int t = __shfl_up(incl, off, 64);
    if (lane >= off) incl += t;
  }
  if (lane == 63) wsum[wv] = incl;
  __syncthreads();
  int add = 0;
  for (int ww = 0; ww < wv; ++ww) add += wsum[ww];
  int excl = add + incl - v;
  curs[tid] = excl;
  int node = b * 256 + tid;
  if (node < N)
    rowptr2[node] = make_uint2((unsigned int)(b * CAPB + excl),
                               (unsigned int)(b * CAPB + excl + v));
  __syncthreads();
  for (int i = tid; i < c; i += 256) {
    unsigned int wd = reg[i];
    int p = atomicAdd(&curs[wd & 255u], 1);
    csrc[(size_t)b * CAPB + p] = (int)(wd >> 8);
  }
}

// ---------------------------------------------------------------------------
// CSR aggregate, 4-deep gather window (e+=16): with deg~Poisson(10), one
// iteration covers ~97% of nodes with 4 independent gathers in flight per
// lane (was 2 iterations x 2 -> latency-bound at 2.3 TB/s effective).
// RAW=false: H = relu(sum/deg + bias + Yr). RAW=true: A = sum/deg.
template <bool RAW>
__global__ __launch_bounds__(256) void k_agg(
    const unsigned short* __restrict__ Y, const uint2* __restrict__ rowptr2,
    const int* __restrict__ csrc, const float* __restrict__ bias,
    const unsigned short* __restrict__ Yr, unsigned short* __restrict__ H,
    int N) {
  int node = (blockIdx.x * 256 + threadIdx.x) >> 6;
  if (node >= N) return;
  const int lane = threadIdx.x & 63;
  const int c4 = lane & 15, rr = lane >> 4;
  uint2 be = rowptr2[node];
  int beg = (int)be.x, end = (int)be.y;
  float a0 = 0.f, a1 = 0.f, a2 = 0.f, a3 = 0.f;
  float b0 = 0.f, b1 = 0.f, b2 = 0.f, b3 = 0.f;
  for (int e = beg; e < end; e += 16) {
    int e0 = e + rr, e1 = e + 4 + rr, e2 = e + 8 + rr, e3 = e + 12 + rr;
    bool p0 = e0 < end, p1 = e1 < end, p2 = e2 < end, p3 = e3 < end;
    int s0 = p0 ? csrc[e0] : 0;
    int s1 = p1 ? csrc[e1] : 0;
    int s2 = p2 ? csrc[e2] : 0;
    int s3 = p3 ? csrc[e3] : 0;
    uint2 v0, v1, v2, v3;
    if (p0) v0 = *(const uint2*)(Y + (size_t)s0 * 64 + c4 * 4);
    if (p1) v1 = *(const uint2*)(Y + (size_t)s1 * 64 + c4 * 4);
    if (p2) v2 = *(const uint2*)(Y + (size_t)s2 * 64 + c4 * 4);
    if (p3) v3 = *(const uint2*)(Y + (size_t)s3 * 64 + c4 * 4);
    if (p0) {
      a0 += bf2f(v0.x & 0xffffu); a1 += bf2f(v0.x >> 16);
      a2 += bf2f(v0.y & 0xffffu); a3 += bf2f(v0.y >> 16);
    }
    if (p1) {
      b0 += bf2f(v1.x & 0xffffu); b1 += bf2f(v1.x >> 16);
      b2 += bf2f(v1.y & 0xffffu); b3 += bf2f(v1.y >> 16);
    }
    if (p2) {
      a0 += bf2f(v2.x & 0xffffu); a1 += bf2f(v2.x >> 16);
      a2 += bf2f(v2.y & 0xffffu); a3 += bf2f(v2.y >> 16);
    }
    if (p3) {
      b0 += bf2f(v3.x & 0xffffu); b1 += bf2f(v3.x >> 16);
      b2 += bf2f(v3.y & 0xffffu); b3 += bf2f(v3.y >> 16);
    }
  }
  a0 += b0; a1 += b1; a2 += b2; a3 += b3;
#pragma unroll
  for (int msk = 16; msk <= 32; msk <<= 1) {
    a0 += __shfl_xor(a0, msk, 64);
    a1 += __shfl_xor(a1, msk, 64);
    a2 += __shfl_xor(a2, msk, 64);
    a3 += __shfl_xor(a3, msk, 64);
  }
  if (rr == 0) {
    float cdeg = (float)(end - beg);
    if (cdeg < 1.f) cdeg = 1.f;
    float inv = 1.f / cdeg;
    float o0, o1, o2, o3;
    if constexpr (RAW) {
      o0 = a0 * inv; o1 = a1 * inv; o2 = a2 * inv; o3 = a3 * inv;
    } else {
      float4 bv = *(const float4*)(bias + c4 * 4);
      uint2 yv = *(const uint2*)(Yr + (size_t)node * 64 + c4 * 4);
      o0 = fmaxf(a0 * inv + bv.x + bf2f(yv.x & 0xffffu), 0.f);
      o1 = fmaxf(a1 * inv + bv.y + bf2f(yv.x >> 16), 0.f);
      o2 = fmaxf(a2 * inv + bv.z + bf2f(yv.y & 0xffffu), 0.f);
      o3 = fmaxf(a3 * inv + bv.w + bf2f(yv.y >> 16), 0.f);
    }
    uint2 pk;
    pk.x = (unsigned int)f2bf(o0) | ((unsigned int)f2bf(o1) << 16);
    pk.y = (unsigned int)f2bf(o2) | ((unsigned int)f2bf(o3) << 16);
    *(uint2*)(H + (size_t)node * 64 + c4 * 4) = pk;
  }
}

// ---------------------------------------------------------------------------
// FUSED layer-2 + G GEMM (r9 form): H2 = relu([A1|H] @ [Wl1;Wr1] + bl1) in
// registers (K=128 MFMA), LDS, then G = H2 @ Wo1 (K=64 MFMA).
__global__ __launch_bounds__(256) void k_gemm2g(
    const unsigned short* __restrict__ A1, const unsigned short* __restrict__ H,
    const float* __restrict__ bl1, const unsigned short* __restrict__ WnL2T,
    const unsigned short* __restrict__ Wo1T, unsigned short* __restrict__ Gb,
    int N) {
  __shared__ __align__(16) unsigned short sX[64 * 136];
  __shared__ __align__(16) unsigned short sH2[64 * 72];
  const int tid = threadIdx.x;
  const int wv = tid >> 6, lane = tid & 63;
  const int m = lane & 15, q = lane >> 4;
  const int row0 = blockIdx.x * 64;
  const int n = wv * 16 + m;

  short8 bB1[4], bB2[2];
#pragma unroll
  for (int c = 0; c < 4; ++c)
    bB1[c] = *(const short8*)(WnL2T + (size_t)n * 128 + c * 32 + q * 8);
#pragma unroll
  for (int c = 0; c < 2; ++c)
    bB2[c] = *(const short8*)(Wo1T + (size_t)n * 64 + c * 32 + q * 8);
  const float bl = bl1[n];

  // stage [A1|H]: 64 rows x 128 bf16 cols; cols 0-63 = A1, 64-127 = H
#pragma unroll
  for (int i = 0; i < 8; ++i) {
    int f = tid + 256 * i;        // 2048 uint2 quads
    int r = f >> 5;               // 32 quads per row
    int c4 = f & 31;
    int rr = row0 + r; if (rr >= N) rr = N - 1;
    uint2 pk;
    if (c4 < 16) pk = *(const uint2*)(A1 + (size_t)rr * 64 + c4 * 4);
    else         pk = *(const uint2*)(H  + (size_t)rr * 64 + (c4 - 16) * 4);
    *(uint2*)(sX + r * 136 + c4 * 4) = pk;
  }
  __syncthreads();

  // stage 1: K=128 MFMA -> H2
  f32x4 acc[4];
#pragma unroll
  for (int rt = 0; rt < 4; ++rt)
#pragma unroll
    for (int r = 0; r < 4; ++r) acc[rt][r] = 0.f;
#pragma unroll
  for (int c = 0; c < 4; ++c)
#pragma unroll
    for (int rt = 0; rt < 4; ++rt) {
      short8 a = *(const short8*)(sX + (rt * 16 + m) * 136 + c * 32 + q * 8);
      acc[rt] = __builtin_amdgcn_mfma_f32_16x16x32_bf16(a, bB1[c], acc[rt], 0, 0, 0);
    }

  // H2 = relu(acc + bl1) -> LDS (A-frag layout, stride 72)
#pragma unroll
  for (int rt = 0; rt < 4; ++rt)
#pragma unroll
    for (int reg = 0; reg < 4; ++reg)
      sH2[(rt * 16 + q * 4 + reg) * 72 + n] = f2bf(fmaxf(acc[rt][reg] + bl, 0.f));
  __syncthreads();

  // stage 2: K=64 MFMA -> G
  f32x4 acc2[4];
#pragma unroll
  for (int rt = 0; rt < 4; ++rt)
#pragma unroll
    for (int r = 0; r < 4; ++r) acc2[rt][r] = 0.f;
#pragma unroll
  for (int c = 0; c < 2; ++c)
#pragma unroll
    for (int rt = 0; rt < 4; ++rt) {
      short8 a = *(const short8*)(sH2 + (rt * 16 + m) * 72 + c * 32 + q * 8);
      acc2[rt] = __builtin_amdgcn_mfma_f32_16x16x32_bf16(a, bB2[c], acc2[rt], 0, 0, 0);
    }

#pragma unroll
  for (int rt = 0; rt < 4; ++rt)
#pragma unroll
    for (int reg = 0; reg < 4; ++reg) {
      int row = row0 + rt * 16 + q * 4 + reg;
      if (row < N) Gb[(size_t)row * 64 + n] = f2bf(acc2[rt][reg]);
    }
}

// ---------------------------------------------------------------------------
// MFMA edge pipeline v3 (known-good 70us form, untouched).
#define T1_STRIDE 72
#define G_STRIDE 68
__global__ __launch_bounds__(256) void k_edge3(
    const unsigned short* __restrict__ EAb, const int* __restrict__ src,
    const int* __restrict__ tgt, const unsigned short* __restrict__ Gb,
    const unsigned short* __restrict__ We1T,
    const unsigned short* __restrict__ W25T,
    const float* __restrict__ cvec, const float* __restrict__ be1,
    const float* __restrict__ Wo2, const float* __restrict__ bo2,
    float* __restrict__ out, int E, int nT, int nWaves) {
  __shared__ unsigned short sT1a[4][16 * T1_STRIDE];
  __shared__ float sGa[4][16 * G_STRIDE];
  const int tid = threadIdx.x;
  const int wid = tid >> 6, lane = tid & 63;
  const int m = lane & 15, q = lane >> 4;
  unsigned short* sT1 = sT1a[wid];
  float* sG = sGa[wid];

  short8 bWe1[4], bW25[4][2];
  float cv[4], wo2v[4], be1v[4];
#pragma unroll
  for (int nt = 0; nt < 4; ++nt) {
    int n = nt * 16 + m;
    bWe1[nt] = *(const short8*)(We1T + n * 32 + q * 8);
    bW25[nt][0] = *(const short8*)(W25T + n * 64 + q * 8);
    bW25[nt][1] = *(const short8*)(W25T + n * 64 + 32 + q * 8);
    cv[nt] = cvec[n];
    wo2v[nt] = Wo2[n];
    be1v[nt] = be1[n];
  }
  const float b_out = bo2[0];
  const short8 zfrag = {};

  int t = blockIdx.x * 4 + wid;
  if (t >= nT) return;
  int il = t * 16 + m; if (il >= E) il = E - 1;
  int my_idx = (lane < 16) ? src[il] : ((lane < 32) ? tgt[il] : 0);

  while (true) {
    const int base = t * 16;
    const int tn = t + nWaves;
    const bool last = (tn >= nT);
    const int tc = last ? t : tn;

    int il_n = tc * 16 + m; if (il_n >= E) il_n = E - 1;
    int idx_n = (lane < 16) ? src[il_n] : ((lane < 32) ? tgt[il_n] : 0);

    int rs[4], rt[4];
#pragma unroll
    for (int r = 0; r < 4; ++r) {
      rs[r] = __shfl(my_idx, q * 4 + r, 64);
      rt[r] = __shfl(my_idx, 16 + q * 4 + r, 64);
    }
    uint2 sv[4], tv[4];
#pragma unroll
    for (int r = 0; r < 4; ++r) {
      sv[r] = *(const uint2*)(Gb + (size_t)rs[r] * 64 + m * 4);
      tv[r] = *(const uint2*)(Gb + (size_t)rt[r] * 64 + m * 4);
    }

    int er = base + m; if (er >= E) er = E - 1;
    short8 aEA = zfrag;
    if (q < 2) aEA = *(const short8*)(EAb + (size_t)er * 16 + (q & 1) * 8);

    f32x4 t1[4];
#pragma unroll
    for (int nt = 0; nt < 4; ++nt) {
      f32x4 cinit; cinit[0] = be1v[nt]; cinit[1] = be1v[nt];
      cinit[2] = be1v[nt]; cinit[3] = be1v[nt];
      t1[nt] = __builtin_amdgcn_mfma_f32_16x16x32_bf16(aEA, bWe1[nt], cinit, 0, 0, 0);
    }
#pragma unroll
    for (int nt = 0; nt < 4; ++nt)
#pragma unroll
      for (int r = 0; r < 4; ++r)
        sT1[(q * 4 + r) * T1_STRIDE + nt * 16 + m] = f2bf(fmaxf(t1[nt][r], 0.f));
    short8 aT0 = *(short8*)(sT1 + m * T1_STRIDE + q * 8);
    short8 aT1 = *(short8*)(sT1 + m * T1_STRIDE + 32 + q * 8);

#pragma unroll
    for (int r = 0; r < 4; ++r) {
      f32x4 g;
      g[0] = bf2f(sv[r].x & 0xffffu) + bf2f(tv[r].x & 0xffffu);
      g[1] = bf2f(sv[r].x >> 16)     + bf2f(tv[r].x >> 16);
      g[2] = bf2f(sv[r].y & 0xffffu) + bf2f(tv[r].y & 0xffffu);
      g[3] = bf2f(sv[r].y >> 16)     + bf2f(tv[r].y >> 16);
      *(f32x4*)(sG + (q * 4 + r) * G_STRIDE + m * 4) = g;
    }

    f32x4 acc[4];
#pragma unroll
    for (int nt = 0; nt < 4; ++nt)
#pragma unroll
      for (int r = 0; r < 4; ++r)
        acc[nt][r] = cv[nt] + sG[(q * 4 + r) * G_STRIDE + nt * 16 + m];
#pragma unroll
    for (int nt = 0; nt < 4; ++nt) {
      acc[nt] = __builtin_amdgcn_mfma_f32_16x16x32_bf16(aT0, bW25[nt][0], acc[nt], 0, 0, 0);
      acc[nt] = __builtin_amdgcn_mfma_f32_16x16x32_bf16(aT1, bW25[nt][1], acc[nt], 0, 0, 0);
    }

    float p[4];
#pragma unroll
    for (int r = 0; r < 4; ++r) {
      p[r] = fmaxf(acc[0][r], 0.f) * wo2v[0] + fmaxf(acc[1][r], 0.f) * wo2v[1] +
             fmaxf(acc[2][r], 0.f) * wo2v[2] + fmaxf(acc[3][r], 0.f) * wo2v[3];
    }
#pragma unroll
    for (int msk = 1; msk <= 8; msk <<= 1) {
#pragma unroll
      for (int r = 0; r < 4; ++r) p[r] += __shfl_xor(p[r], msk, 64);
    }
    if (m == 0) {
#pragma unroll
      for (int r = 0; r < 4; ++r) {
        int row = base + q * 4 + r;
        if (row < E) out[row] = 1.f / (1.f + __expf(-(p[r] + b_out)));
      }
    }

    if (last) break;
    t = tn; my_idx = idx_n;
  }
}

// ---------------------------------------------------------------------------
extern "C" void kernel_launch(void* const* d_in, const int* in_sizes, int n_in,
                              void* d_out, int out_size, void* d_ws, size_t ws_size,
                              hipStream_t stream) {
  const float* x     = (const float*)d_in[0];
  const unsigned int* eidx = (const unsigned int*)d_in[1];
  const float* eattr = (const float*)d_in[2];
  const float* We1 = (const float*)d_in[3];
  const float* be1 = (const float*)d_in[4];
  const float* We2 = (const float*)d_in[5];
  const float* be2 = (const float*)d_in[6];
  const float* Wl0 = (const float*)d_in[7];
  const float* bl0 = (const float*)d_in[8];
  const float* Wr0 = (const float*)d_in[9];
  const float* Wl1 = (const float*)d_in[10];
  const float* bl1 = (const float*)d_in[11];
  const float* Wr1 = (const float*)d_in[12];
  const float* Wo1 = (const float*)d_in[13];
  const float* bo1 = (const float*)d_in[14];
  const float* Wo2 = (const float*)d_in[15];
  const float* bo2 = (const float*)d_in[16];

  const int N = in_sizes[0] / 128;   // 100000
  const int E = in_sizes[2] / 16;    // 1000000
  const int NBUCK = (N + 255) >> 8;  // 391 coarse buckets (tgt>>8)
  float* out = (float*)d_out;

  char* ws = (char*)d_ws;
  size_t off = 0;
  auto alloc = [&](size_t bytes) {
    char* p = ws + off;
    off += (bytes + 255) & ~(size_t)255;
    return p;
  };
  unsigned int* flag = (unsigned int*)alloc(256);
  int* src    = (int*)alloc((size_t)E * 4);
  int* tgt    = (int*)alloc((size_t)E * 4);
  int* gcursor = (int*)alloc(512 * 4);
  unsigned int* tmp = (unsigned int*)alloc((size_t)NBUCK * CAPB * 4);
  int* csrc   = (int*)alloc((size_t)NBUCK * CAPB * 4);
  uint2* rowptr2 = (uint2*)alloc((size_t)N * 8);
  unsigned short* EAb = (unsigned short*)alloc((size_t)E * 16 * 2);
  unsigned short* Hb = (unsigned short*)alloc((size_t)N * 64 * 2);
  unsigned short* A1 = (unsigned short*)alloc((size_t)N * 64 * 2);
  unsigned short* Yl = (unsigned short*)alloc((size_t)N * 64 * 2);
  unsigned short* Yr = (unsigned short*)alloc((size_t)N * 64 * 2);
  unsigned short* Gb = (unsigned short*)alloc((size_t)N * 64 * 2);
  unsigned short* W25T = (unsigned short*)alloc(64 * 64 * 2);
  unsigned short* We1T = (unsigned short*)alloc(64 * 32 * 2);
  unsigned short* Wo1T = (unsigned short*)alloc(64 * 64 * 2);
  unsigned short* WnL2T = (unsigned short*)alloc(64 * 128 * 2);
  float* cvec = (float*)alloc(64 * 4);
  (void)ws_size; (void)n_in; (void)out_size;

  k_flag<<<2, 256, 0, stream>>>(eidx, 8192, flag, gcursor);

  // MEGA1: decode+scatter + prep + WnL2T + layer-0 GEMM
  const int nDec = (E + 4095) / 4096;   // 245 decode+scatter blocks
  const int gB = (N + 63) / 64;
  const int nWork = 33 + gB;
  k_mega1<<<nDec + nWork, 256, 0, stream>>>(
      eidx, flag, E, nDec, nWork, gB,
      src, tgt, gcursor, tmp,
      x, Yl, Yr, N,
      We2, Wo1, be2, bo1, We1, Wl0, Wr0, Wl1, Wr1,
      W25T, We1T, Wo1T, cvec, WnL2T);

  // bsort (391 long-pole blocks first) + co-dispatched eattr conv
  const int nConv = (E * 4 + 1023) / 1024;   // 3907 conv blocks
  k_bsort<<<NBUCK + nConv, 256, 0, stream>>>(tmp, gcursor, csrc, rowptr2, N,
                                             NBUCK, (const float4*)eattr,
                                             (uint2*)EAb, E * 4);

  const int aggB = (N + 3) / 4;
  // agg0: H = relu(mean(Yl[src]) + bl0 + Yr)
  k_agg<false><<<aggB, 256, 0, stream>>>(Yl, rowptr2, csrc, bl0, Yr, Hb, N);
  // agg1': A1 = mean(H[src])  (raw mean; linearity moves Wl1 after the agg)
  k_agg<true><<<aggB, 256, 0, stream>>>(Hb, rowptr2, csrc, nullptr, nullptr,
                                        A1, N);
  // fused layer-2 + G: H2 = relu([A1|H]@[Wl1;Wr1]+bl1); G = H2@Wo1
  k_gemm2g<<<gB, 256, 0, stream>>>(A1, Hb, bl1, WnL2T, Wo1T, Gb, N);

  // MFMA edge pipeline v3
  const int nT = (E + 15) / 16;
  const int blocks = 3072;
  k_edge3<<<blocks, 256, 0, stream>>>(EAb, src, tgt, Gb, We1T, W25T, cvec,
                                      be1, Wo2, bo2, out, E, nT, blocks * 4);
}

// Round 11
// 377.068 us; speedup vs baseline: 1.0325x; 1.0325x over previous
//
#include <hip/hip_runtime.h>
#include <math.h>

typedef __attribute__((ext_vector_type(8))) short short8;
typedef __attribute__((ext_vector_type(4))) float f32x4;

#define CAPB 4096   // fixed capacity per coarse bucket (mean 2558, 30 sigma)

static __device__ __forceinline__ unsigned short f2bf(float f) {
  union { float f; unsigned int u; } x; x.f = f;
  unsigned int r = x.u + 0x7fffu + ((x.u >> 16) & 1u);  // RNE
  return (unsigned short)(r >> 16);
}
static __device__ __forceinline__ float bf2f(unsigned int u) {
  union { unsigned int u; float f; } x; x.u = u << 16; return x.f;
}

// ---------------------------------------------------------------------------
// Block 0: int64-vs-int32 edge_index detection. Block 1: zero gcursor[512].
__global__ void k_flag(const unsigned int* __restrict__ w, int nSample,
                       unsigned int* __restrict__ flag,
                       int* __restrict__ gcursor) {
  if (blockIdx.x == 1) {
    if (threadIdx.x < 256) { gcursor[threadIdx.x] = 0; gcursor[threadIdx.x + 256] = 0; }
    return;
  }
  if (blockIdx.x != 0) return;
  __shared__ unsigned int red[256];
  unsigned int v = 0;
  for (int i = threadIdx.x; i < nSample; i += 256) v |= w[2 * i + 1];
  red[threadIdx.x] = v;
  __syncthreads();
  for (int s = 128; s > 0; s >>= 1) {
    if (threadIdx.x < s) red[threadIdx.x] |= red[threadIdx.x + s];
    __syncthreads();
  }
  if (threadIdx.x == 0) flag[0] = red[0];  // nonzero => int32 layout
}

// ---------------------------------------------------------------------------
// MFMA node GEMM body. INLINEW: build B fragments directly from f32 W0/W1.
// MFMA layouts (gfx950, verified): A[m=lane&15][k=(lane>>4)*8+j],
// B[k][n=lane&15], C/D col=lane&15, row=(lane>>4)*4+reg.
template <int K, bool BF16IN, int NTILES, bool INLINEW>
__device__ __forceinline__ void ngemm_body(
    const void* __restrict__ Xv, const unsigned short* __restrict__ WnT,
    const float* __restrict__ W0f, const float* __restrict__ W1f,
    unsigned short* __restrict__ Y0, unsigned short* __restrict__ Y1,
    int N, int blk, unsigned short* __restrict__ sX) {
  constexpr int STR = K + 8;
  constexpr int NC = K / 32;
  const int tid = threadIdx.x;
  const int wv = tid >> 6, lane = tid & 63;
  const int m = lane & 15, q = lane >> 4;
  const int row0 = blk * 64;

  short8 bB[NTILES][NC];
#pragma unroll
  for (int ct = 0; ct < NTILES; ++ct)
#pragma unroll
    for (int c = 0; c < NC; ++c) {
      if constexpr (INLINEW) {
        int n = (NTILES == 2) ? (wv * 32 + ct * 16 + m) : (wv * 16 + m);
        const float* Wf = (n < 64) ? W0f : W1f;
        int nn = n & 63;
        union { short8 s; unsigned short h[8]; } ub;
#pragma unroll
        for (int j = 0; j < 8; ++j)
          ub.h[j] = f2bf(Wf[(size_t)(c * 32 + q * 8 + j) * 64 + nn]);
        bB[ct][c] = ub.s;
      } else {
        int n = (NTILES == 2) ? (wv * 32 + ct * 16 + m) : (wv * 16 + m);
        bB[ct][c] = *(const short8*)(WnT + (size_t)n * K + c * 32 + q * 8);
      }
    }

#pragma unroll
  for (int i = 0; i < K / 16; ++i) {
    int f = tid + 256 * i;
    int r = f / (K / 4);
    int c4 = f % (K / 4);
    int rr = row0 + r; if (rr >= N) rr = N - 1;
    uint2 pk;
    if constexpr (BF16IN) {
      pk = *(const uint2*)((const unsigned short*)Xv + (size_t)rr * K + c4 * 4);
    } else {
      float4 v = *(const float4*)((const float*)Xv + (size_t)rr * K + c4 * 4);
      pk.x = (unsigned int)f2bf(v.x) | ((unsigned int)f2bf(v.y) << 16);
      pk.y = (unsigned int)f2bf(v.z) | ((unsigned int)f2bf(v.w) << 16);
    }
    *(uint2*)(sX + r * STR + c4 * 4) = pk;
  }
  __syncthreads();

  f32x4 acc[4][NTILES];
#pragma unroll
  for (int rt = 0; rt < 4; ++rt)
#pragma unroll
    for (int ct = 0; ct < NTILES; ++ct)
#pragma unroll
      for (int r = 0; r < 4; ++r) acc[rt][ct][r] = 0.f;

#pragma unroll
  for (int c = 0; c < NC; ++c) {
    short8 a[4];
#pragma unroll
    for (int rt = 0; rt < 4; ++rt)
      a[rt] = *(const short8*)(sX + (rt * 16 + m) * STR + c * 32 + q * 8);
#pragma unroll
    for (int rt = 0; rt < 4; ++rt)
#pragma unroll
      for (int ct = 0; ct < NTILES; ++ct)
        acc[rt][ct] = __builtin_amdgcn_mfma_f32_16x16x32_bf16(a[rt], bB[ct][c], acc[rt][ct], 0, 0, 0);
  }

#pragma unroll
  for (int rt = 0; rt < 4; ++rt)
#pragma unroll
    for (int ct = 0; ct < NTILES; ++ct) {
      unsigned short* Yw;
      int n;
      if constexpr (NTILES == 2) {
        Yw = (wv < 2) ? Y0 : Y1;
        n = (wv & 1) * 32 + ct * 16 + m;
      } else {
        Yw = Y0;
        n = wv * 16 + m;
      }
#pragma unroll
      for (int reg = 0; reg < 4; ++reg) {
        int row = row0 + rt * 16 + q * 4 + reg;
        if (row < N) Yw[(size_t)row * 64 + n] = f2bf(acc[rt][ct][reg]);
      }
    }
}

// ---------------------------------------------------------------------------
// MEGA1: decode+bucket-scatter + prep + WnL2T + layer-0 GEMM (INLINEW).
// Proportional striping so decode blocks co-reside with compute from t=0.
__global__ __launch_bounds__(256) void k_mega1(
    const unsigned int* __restrict__ w, const unsigned int* __restrict__ flag,
    int E, int nDec, int nWork, int gB,
    int* __restrict__ src, int* __restrict__ tgt,
    int* __restrict__ gcursor, unsigned int* __restrict__ tmp,
    const float* __restrict__ x, unsigned short* __restrict__ Yl,
    unsigned short* __restrict__ Yr, int N,
    const float* __restrict__ We2, const float* __restrict__ Wo1,
    const float* __restrict__ be2, const float* __restrict__ bo1,
    const float* __restrict__ We1,
    const float* __restrict__ Wl0, const float* __restrict__ Wr0,
    const float* __restrict__ Wl1, const float* __restrict__ Wr1,
    unsigned short* __restrict__ W25T, unsigned short* __restrict__ We1T,
    unsigned short* __restrict__ Wo1T, float* __restrict__ cvec,
    unsigned short* __restrict__ WnL2T) {
  __shared__ __align__(16) char smem[64 * 136 * 2];   // 17408 B, union use
  const int tid = threadIdx.x;
  const int tot = nDec + nWork;
  const int di  = (int)(((long long)blockIdx.x * nDec) / tot);
  const int di1 = (int)(((long long)(blockIdx.x + 1) * nDec) / tot);

  if (di1 > di) {
    // ---- decode+scatter block #di: edges [di*4096, min(E, +4096))
    int* hist = (int*)smem;   // 512 ints
    hist[tid] = 0; hist[tid + 256] = 0;
    __syncthreads();
    const int e0 = di * 4096;
    const int e1 = (e0 + 4096 < E) ? (e0 + 4096) : E;
    const unsigned int fl = flag[0];
    for (int e = e0 + tid; e < e1; e += 256) {
      int s, t;
      if (fl) { s = (int)w[e]; t = (int)w[E + e]; }
      else    { s = (int)w[2 * e]; t = (int)w[2 * (E + e)]; }
      src[e] = s; tgt[e] = t;
      atomicAdd(hist + (t >> 8), 1);
    }
    __syncthreads();
    {
      int c0 = hist[tid], c1 = hist[tid + 256];
      int s0 = (c0 > 0) ? atomicAdd(gcursor + tid, c0) : 0;
      int s1 = (c1 > 0) ? atomicAdd(gcursor + tid + 256, c1) : 0;
      __syncthreads();
      hist[tid] = s0; hist[tid + 256] = s1;
    }
    __syncthreads();
    for (int e = e0 + tid; e < e1; e += 256) {
      int s, t;
      if (fl) { s = (int)w[e]; t = (int)w[E + e]; }
      else    { s = (int)w[2 * e]; t = (int)w[2 * (E + e)]; }
      int b = t >> 8;
      int pos = atomicAdd(hist + b, 1);
      if (pos < CAPB)
        tmp[(size_t)b * CAPB + pos] = ((unsigned int)s << 8) | (unsigned int)(t & 255);
    }
    return;
  }
  const int wi = blockIdx.x - di;
  if (wi == 0) {
    // ---- prep: W25T=(We2@Wo1)^T, Wo1T, We1T, cvec (Wo1 staged in smem)
    float* sB = (float*)smem;
    for (int i = tid; i < 1024; i += 256)
      *(float4*)&sB[i * 4] = *(const float4*)(Wo1 + i * 4);
    __syncthreads();
    for (int idx = tid; idx < 4096; idx += 256) {
      int k = idx >> 6, n = idx & 63;   // k wave-uniform -> We2 scalarizes
      float s = 0.f;
#pragma unroll 8
      for (int mm = 0; mm < 64; ++mm) s = fmaf(We2[k * 64 + mm], sB[mm * 64 + n], s);
      W25T[n * 64 + k] = f2bf(s);
      Wo1T[n * 64 + k] = f2bf(sB[k * 64 + n]);
    }
    for (int idx = tid; idx < 2048; idx += 256) {
      int n = idx >> 5, k = idx & 31;
      We1T[n * 32 + k] = (k < 16) ? f2bf(We1[k * 64 + n]) : (unsigned short)0;
    }
    if (tid < 64) {
      float s = bo1[tid];
#pragma unroll 8
      for (int mm = 0; mm < 64; ++mm) s = fmaf(be2[mm], sB[mm * 64 + tid], s);
      cvec[tid] = s;
    }
  } else if (wi <= 32) {
    // ---- WnL2T: [64 n][128 k], k<64 from Wl1, k>=64 from Wr1 (stacked K)
    int idx = (wi - 1) * 256 + tid;   // 0..8191
    int n = idx >> 7, k = idx & 127;
    float v = (k < 64) ? Wl1[(size_t)k * 64 + n]
                       : Wr1[(size_t)(k - 64) * 64 + n];
    WnL2T[idx] = f2bf(v);
  } else {
    // ---- layer-0 GEMM (inline f32 weights)
    ngemm_body<128, false, 2, true>(x, nullptr, Wl0, Wr0, Yl, Yr, N,
                                    wi - 33, (unsigned short*)smem);
  }
}

// ---------------------------------------------------------------------------
// Per-bucket counting sort + co-dispatched eattr conv (r8 form).
__global__ __launch_bounds__(256) void k_bsort(
    const unsigned int* __restrict__ tmp, const int* __restrict__ gcursor,
    int* __restrict__ csrc, uint2* __restrict__ rowptr2, int N, int nBuck,
    const float4* __restrict__ ef, uint2* __restrict__ eb, int nItems) {
  __shared__ int cnt[256];
  __shared__ int curs[256];
  __shared__ int wsum[4];
  const int tid = threadIdx.x;
  if (blockIdx.x >= nBuck) {
    const int ci = blockIdx.x - nBuck;
#pragma unroll
    for (int j = 0; j < 4; ++j) {
      int i = ci * 1024 + j * 256 + tid;
      if (i < nItems) {
        float4 v = ef[i];
        uint2 pk;
        pk.x = (unsigned int)f2bf(v.x) | ((unsigned int)f2bf(v.y) << 16);
        pk.y = (unsigned int)f2bf(v.z) | ((unsigned int)f2bf(v.w) << 16);
        eb[i] = pk;
      }
    }
    return;
  }
  const int b = blockIdx.x;
  int c = gcursor[b]; if (c > CAPB) c = CAPB;
  cnt[tid] = 0;
  __syncthreads();
  const unsigned int* reg = tmp + (size_t)b * CAPB;
  for (int i = tid; i < c; i += 256) atomicAdd(&cnt[reg[i] & 255u], 1);
  __syncthreads();
  const int lane = tid & 63, wv = tid >> 6;
  int v = cnt[tid];
  int incl = v;
#pragma unroll
  for (int off = 1; off < 64; off <<= 1) {
    int t = __shfl_up(incl, off, 64);
    if (lane >= off) incl += t;
  }
  if (lane == 63) wsum[wv] = incl;
  __syncthreads();
  int add = 0;
  for (int ww = 0; ww < wv; ++ww) add += wsum[ww];
  int excl = add + incl - v;
  curs[tid] = excl;
  int node = b * 256 + tid;
  if (node < N)
    rowptr2[node] = make_uint2((unsigned int)(b * CAPB + excl),
                               (unsigned int)(b * CAPB + excl + v));
  __syncthreads();
  for (int i = tid; i < c; i += 256) {
    unsigned int wd = reg[i];
    int p = atomicAdd(&curs[wd & 255u], 1);
    csrc[(size_t)b * CAPB + p] = (int)(wd >> 8);
  }
}

// ---------------------------------------------------------------------------
// CSR aggregate v3 — request-halved: lane layout 8 edge-slots x 8 col-octs,
// each lane loads uint4 (16B). Per edge-row: 8 requests (was 16 x uint2);
// 16 edges in flight per wave per iteration. r10's null ILP result implies
// the gather path is TA-request-rate-bound, not latency-bound -> halving
// transactions is the lever. RAW=false: H = relu(sum/deg + bias + Yr).
// RAW=true: A = sum/deg.
template <bool RAW>
__global__ __launch_bounds__(256) void k_agg(
    const unsigned short* __restrict__ Y, const uint2* __restrict__ rowptr2,
    const int* __restrict__ csrc, const float* __restrict__ bias,
    const unsigned short* __restrict__ Yr, unsigned short* __restrict__ H,
    int N) {
  int node = (blockIdx.x * 256 + threadIdx.x) >> 6;
  if (node >= N) return;
  const int lane = threadIdx.x & 63;
  const int c8 = lane & 7;    // col-oct: cols [c8*8, c8*8+8)
  const int rr = lane >> 3;   // 8 edge slots
  uint2 be = rowptr2[node];
  int beg = (int)be.x, end = (int)be.y;
  float a0 = 0.f, a1 = 0.f, a2 = 0.f, a3 = 0.f;
  float a4 = 0.f, a5 = 0.f, a6 = 0.f, a7 = 0.f;
  float b0 = 0.f, b1 = 0.f, b2 = 0.f, b3 = 0.f;
  float b4 = 0.f, b5 = 0.f, b6 = 0.f, b7 = 0.f;
  for (int e = beg; e < end; e += 16) {
    int e0 = e + rr, e1 = e + 8 + rr;
    bool p0 = e0 < end, p1 = e1 < end;
    int s0 = p0 ? csrc[e0] : 0;
    int s1 = p1 ? csrc[e1] : 0;
    uint4 v0, v1;
    if (p0) v0 = *(const uint4*)(Y + (size_t)s0 * 64 + c8 * 8);
    if (p1) v1 = *(const uint4*)(Y + (size_t)s1 * 64 + c8 * 8);
    if (p0) {
      a0 += bf2f(v0.x & 0xffffu); a1 += bf2f(v0.x >> 16);
      a2 += bf2f(v0.y & 0xffffu); a3 += bf2f(v0.y >> 16);
      a4 += bf2f(v0.z & 0xffffu); a5 += bf2f(v0.z >> 16);
      a6 += bf2f(v0.w & 0xffffu); a7 += bf2f(v0.w >> 16);
    }
    if (p1) {
      b0 += bf2f(v1.x & 0xffffu); b1 += bf2f(v1.x >> 16);
      b2 += bf2f(v1.y & 0xffffu); b3 += bf2f(v1.y >> 16);
      b4 += bf2f(v1.z & 0xffffu); b5 += bf2f(v1.z >> 16);
      b6 += bf2f(v1.w & 0xffffu); b7 += bf2f(v1.w >> 16);
    }
  }
  a0 += b0; a1 += b1; a2 += b2; a3 += b3;
  a4 += b4; a5 += b5; a6 += b6; a7 += b7;
#pragma unroll
  for (int msk = 8; msk <= 32; msk <<= 1) {
    a0 += __shfl_xor(a0, msk, 64);
    a1 += __shfl_xor(a1, msk, 64);
    a2 += __shfl_xor(a2, msk, 64);
    a3 += __shfl_xor(a3, msk, 64);
    a4 += __shfl_xor(a4, msk, 64);
    a5 += __shfl_xor(a5, msk, 64);
    a6 += __shfl_xor(a6, msk, 64);
    a7 += __shfl_xor(a7, msk, 64);
  }
  if (rr == 0) {
    float cdeg = (float)(end - beg);
    if (cdeg < 1.f) cdeg = 1.f;
    float inv = 1.f / cdeg;
    float o0, o1, o2, o3, o4, o5, o6, o7;
    if constexpr (RAW) {
      o0 = a0 * inv; o1 = a1 * inv; o2 = a2 * inv; o3 = a3 * inv;
      o4 = a4 * inv; o5 = a5 * inv; o6 = a6 * inv; o7 = a7 * inv;
    } else {
      float4 bv0 = *(const float4*)(bias + c8 * 8);
      float4 bv1 = *(const float4*)(bias + c8 * 8 + 4);
      uint4 yv = *(const uint4*)(Yr + (size_t)node * 64 + c8 * 8);
      o0 = fmaxf(a0 * inv + bv0.x + bf2f(yv.x & 0xffffu), 0.f);
      o1 = fmaxf(a1 * inv + bv0.y + bf2f(yv.x >> 16), 0.f);
      o2 = fmaxf(a2 * inv + bv0.z + bf2f(yv.y & 0xffffu), 0.f);
      o3 = fmaxf(a3 * inv + bv0.w + bf2f(yv.y >> 16), 0.f);
      o4 = fmaxf(a4 * inv + bv1.x + bf2f(yv.z & 0xffffu), 0.f);
      o5 = fmaxf(a5 * inv + bv1.y + bf2f(yv.z >> 16), 0.f);
      o6 = fmaxf(a6 * inv + bv1.z + bf2f(yv.w & 0xffffu), 0.f);
      o7 = fmaxf(a7 * inv + bv1.w + bf2f(yv.w >> 16), 0.f);
    }
    uint4 pk;
    pk.x = (unsigned int)f2bf(o0) | ((unsigned int)f2bf(o1) << 16);
    pk.y = (unsigned int)f2bf(o2) | ((unsigned int)f2bf(o3) << 16);
    pk.z = (unsigned int)f2bf(o4) | ((unsigned int)f2bf(o5) << 16);
    pk.w = (unsigned int)f2bf(o6) | ((unsigned int)f2bf(o7) << 16);
    *(uint4*)(H + (size_t)node * 64 + c8 * 8) = pk;
  }
}

// ---------------------------------------------------------------------------
// FUSED layer-2 + G GEMM (r9 form): H2 = relu([A1|H] @ [Wl1;Wr1] + bl1) in
// registers (K=128 MFMA), LDS, then G = H2 @ Wo1 (K=64 MFMA).
__global__ __launch_bounds__(256) void k_gemm2g(
    const unsigned short* __restrict__ A1, const unsigned short* __restrict__ H,
    const float* __restrict__ bl1, const unsigned short* __restrict__ WnL2T,
    const unsigned short* __restrict__ Wo1T, unsigned short* __restrict__ Gb,
    int N) {
  __shared__ __align__(16) unsigned short sX[64 * 136];
  __shared__ __align__(16) unsigned short sH2[64 * 72];
  const int tid = threadIdx.x;
  const int wv = tid >> 6, lane = tid & 63;
  const int m = lane & 15, q = lane >> 4;
  const int row0 = blockIdx.x * 64;
  const int n = wv * 16 + m;

  short8 bB1[4], bB2[2];
#pragma unroll
  for (int c = 0; c < 4; ++c)
    bB1[c] = *(const short8*)(WnL2T + (size_t)n * 128 + c * 32 + q * 8);
#pragma unroll
  for (int c = 0; c < 2; ++c)
    bB2[c] = *(const short8*)(Wo1T + (size_t)n * 64 + c * 32 + q * 8);
  const float bl = bl1[n];

  // stage [A1|H]: 64 rows x 128 bf16 cols; cols 0-63 = A1, 64-127 = H
#pragma unroll
  for (int i = 0; i < 8; ++i) {
    int f = tid + 256 * i;        // 2048 uint2 quads
    int r = f >> 5;               // 32 quads per row
    int c4 = f & 31;
    int rr = row0 + r; if (rr >= N) rr = N - 1;
    uint2 pk;
    if (c4 < 16) pk = *(const uint2*)(A1 + (size_t)rr * 64 + c4 * 4);
    else         pk = *(const uint2*)(H  + (size_t)rr * 64 + (c4 - 16) * 4);
    *(uint2*)(sX + r * 136 + c4 * 4) = pk;
  }
  __syncthreads();

  // stage 1: K=128 MFMA -> H2
  f32x4 acc[4];
#pragma unroll
  for (int rt = 0; rt < 4; ++rt)
#pragma unroll
    for (int r = 0; r < 4; ++r) acc[rt][r] = 0.f;
#pragma unroll
  for (int c = 0; c < 4; ++c)
#pragma unroll
    for (int rt = 0; rt < 4; ++rt) {
      short8 a = *(const short8*)(sX + (rt * 16 + m) * 136 + c * 32 + q * 8);
      acc[rt] = __builtin_amdgcn_mfma_f32_16x16x32_bf16(a, bB1[c], acc[rt], 0, 0, 0);
    }

  // H2 = relu(acc + bl1) -> LDS (A-frag layout, stride 72)
#pragma unroll
  for (int rt = 0; rt < 4; ++rt)
#pragma unroll
    for (int reg = 0; reg < 4; ++reg)
      sH2[(rt * 16 + q * 4 + reg) * 72 + n] = f2bf(fmaxf(acc[rt][reg] + bl, 0.f));
  __syncthreads();

  // stage 2: K=64 MFMA -> G
  f32x4 acc2[4];
#pragma unroll
  for (int rt = 0; rt < 4; ++rt)
#pragma unroll
    for (int r = 0; r < 4; ++r) acc2[rt][r] = 0.f;
#pragma unroll
  for (int c = 0; c < 2; ++c)
#pragma unroll
    for (int rt = 0; rt < 4; ++rt) {
      short8 a = *(const short8*)(sH2 + (rt * 16 + m) * 72 + c * 32 + q * 8);
      acc2[rt] = __builtin_amdgcn_mfma_f32_16x16x32_bf16(a, bB2[c], acc2[rt], 0, 0, 0);
    }

#pragma unroll
  for (int rt = 0; rt < 4; ++rt)
#pragma unroll
    for (int reg = 0; reg < 4; ++reg) {
      int row = row0 + rt * 16 + q * 4 + reg;
      if (row < N) Gb[(size_t)row * 64 + n] = f2bf(acc2[rt][reg]);
    }
}

// ---------------------------------------------------------------------------
// MFMA edge pipeline v3 (known-good 70us form, untouched).
#define T1_STRIDE 72
#define G_STRIDE 68
__global__ __launch_bounds__(256) void k_edge3(
    const unsigned short* __restrict__ EAb, const int* __restrict__ src,
    const int* __restrict__ tgt, const unsigned short* __restrict__ Gb,
    const unsigned short* __restrict__ We1T,
    const unsigned short* __restrict__ W25T,
    const float* __restrict__ cvec, const float* __restrict__ be1,
    const float* __restrict__ Wo2, const float* __restrict__ bo2,
    float* __restrict__ out, int E, int nT, int nWaves) {
  __shared__ unsigned short sT1a[4][16 * T1_STRIDE];
  __shared__ float sGa[4][16 * G_STRIDE];
  const int tid = threadIdx.x;
  const int wid = tid >> 6, lane = tid & 63;
  const int m = lane & 15, q = lane >> 4;
  unsigned short* sT1 = sT1a[wid];
  float* sG = sGa[wid];

  short8 bWe1[4], bW25[4][2];
  float cv[4], wo2v[4], be1v[4];
#pragma unroll
  for (int nt = 0; nt < 4; ++nt) {
    int n = nt * 16 + m;
    bWe1[nt] = *(const short8*)(We1T + n * 32 + q * 8);
    bW25[nt][0] = *(const short8*)(W25T + n * 64 + q * 8);
    bW25[nt][1] = *(const short8*)(W25T + n * 64 + 32 + q * 8);
    cv[nt] = cvec[n];
    wo2v[nt] = Wo2[n];
    be1v[nt] = be1[n];
  }
  const float b_out = bo2[0];
  const short8 zfrag = {};

  int t = blockIdx.x * 4 + wid;
  if (t >= nT) return;
  int il = t * 16 + m; if (il >= E) il = E - 1;
  int my_idx = (lane < 16) ? src[il] : ((lane < 32) ? tgt[il] : 0);

  while (true) {
    const int base = t * 16;
    const int tn = t + nWaves;
    const bool last = (tn >= nT);
    const int tc = last ? t : tn;

    int il_n = tc * 16 + m; if (il_n >= E) il_n = E - 1;
    int idx_n = (lane < 16) ? src[il_n] : ((lane < 32) ? tgt[il_n] : 0);

    int rs[4], rt[4];
#pragma unroll
    for (int r = 0; r < 4; ++r) {
      rs[r] = __shfl(my_idx, q * 4 + r, 64);
      rt[r] = __shfl(my_idx, 16 + q * 4 + r, 64);
    }
    uint2 sv[4], tv[4];
#pragma unroll
    for (int r = 0; r < 4; ++r) {
      sv[r] = *(const uint2*)(Gb + (size_t)rs[r] * 64 + m * 4);
      tv[r] = *(const uint2*)(Gb + (size_t)rt[r] * 64 + m * 4);
    }

    int er = base + m; if (er >= E) er = E - 1;
    short8 aEA = zfrag;
    if (q < 2) aEA = *(const short8*)(EAb + (size_t)er * 16 + (q & 1) * 8);

    f32x4 t1[4];
#pragma unroll
    for (int nt = 0; nt < 4; ++nt) {
      f32x4 cinit; cinit[0] = be1v[nt]; cinit[1] = be1v[nt];
      cinit[2] = be1v[nt]; cinit[3] = be1v[nt];
      t1[nt] = __builtin_amdgcn_mfma_f32_16x16x32_bf16(aEA, bWe1[nt], cinit, 0, 0, 0);
    }
#pragma unroll
    for (int nt = 0; nt < 4; ++nt)
#pragma unroll
      for (int r = 0; r < 4; ++r)
        sT1[(q * 4 + r) * T1_STRIDE + nt * 16 + m] = f2bf(fmaxf(t1[nt][r], 0.f));
    short8 aT0 = *(short8*)(sT1 + m * T1_STRIDE + q * 8);
    short8 aT1 = *(short8*)(sT1 + m * T1_STRIDE + 32 + q * 8);

#pragma unroll
    for (int r = 0; r < 4; ++r) {
      f32x4 g;
      g[0] = bf2f(sv[r].x & 0xffffu) + bf2f(tv[r].x & 0xffffu);
      g[1] = bf2f(sv[r].x >> 16)     + bf2f(tv[r].x >> 16);
      g[2] = bf2f(sv[r].y & 0xffffu) + bf2f(tv[r].y & 0xffffu);
      g[3] = bf2f(sv[r].y >> 16)     + bf2f(tv[r].y >> 16);
      *(f32x4*)(sG + (q * 4 + r) * G_STRIDE + m * 4) = g;
    }

    f32x4 acc[4];
#pragma unroll
    for (int nt = 0; nt < 4; ++nt)
#pragma unroll
      for (int r = 0; r < 4; ++r)
        acc[nt][r] = cv[nt] + sG[(q * 4 + r) * G_STRIDE + nt * 16 + m];
#pragma unroll
    for (int nt = 0; nt < 4; ++nt) {
      acc[nt] = __builtin_amdgcn_mfma_f32_16x16x32_bf16(aT0, bW25[nt][0], acc[nt], 0, 0, 0);
      acc[nt] = __builtin_amdgcn_mfma_f32_16x16x32_bf16(aT1, bW25[nt][1], acc[nt], 0, 0, 0);
    }

    float p[4];
#pragma unroll
    for (int r = 0; r < 4; ++r) {
      p[r] = fmaxf(acc[0][r], 0.f) * wo2v[0] + fmaxf(acc[1][r], 0.f) * wo2v[1] +
             fmaxf(acc[2][r], 0.f) * wo2v[2] + fmaxf(acc[3][r], 0.f) * wo2v[3];
    }
#pragma unroll
    for (int msk = 1; msk <= 8; msk <<= 1) {
#pragma unroll
      for (int r = 0; r < 4; ++r) p[r] += __shfl_xor(p[r], msk, 64);
    }
    if (m == 0) {
#pragma unroll
      for (int r = 0; r < 4; ++r) {
        int row = base + q * 4 + r;
        if (row < E) out[row] = 1.f / (1.f + __expf(-(p[r] + b_out)));
      }
    }

    if (last) break;
    t = tn; my_idx = idx_n;
  }
}

// ---------------------------------------------------------------------------
extern "C" void kernel_launch(void* const* d_in, const int* in_sizes, int n_in,
                              void* d_out, int out_size, void* d_ws, size_t ws_size,
                              hipStream_t stream) {
  const float* x     = (const float*)d_in[0];
  const unsigned int* eidx = (const unsigned int*)d_in[1];
  const float* eattr = (const float*)d_in[2];
  const float* We1 = (const float*)d_in[3];
  const float* be1 = (const float*)d_in[4];
  const float* We2 = (const float*)d_in[5];
  const float* be2 = (const float*)d_in[6];
  const float* Wl0 = (const float*)d_in[7];
  const float* bl0 = (const float*)d_in[8];
  const float* Wr0 = (const float*)d_in[9];
  const float* Wl1 = (const float*)d_in[10];
  const float* bl1 = (const float*)d_in[11];
  const float* Wr1 = (const float*)d_in[12];
  const float* Wo1 = (const float*)d_in[13];
  const float* bo1 = (const float*)d_in[14];
  const float* Wo2 = (const float*)d_in[15];
  const float* bo2 = (const float*)d_in[16];

  const int N = in_sizes[0] / 128;   // 100000
  const int E = in_sizes[2] / 16;    // 1000000
  const int NBUCK = (N + 255) >> 8;  // 391 coarse buckets (tgt>>8)
  float* out = (float*)d_out;

  char* ws = (char*)d_ws;
  size_t off = 0;
  auto alloc = [&](size_t bytes) {
    char* p = ws + off;
    off += (bytes + 255) & ~(size_t)255;
    return p;
  };
  unsigned int* flag = (unsigned int*)alloc(256);
  int* src    = (int*)alloc((size_t)E * 4);
  int* tgt    = (int*)alloc((size_t)E * 4);
  int* gcursor = (int*)alloc(512 * 4);
  unsigned int* tmp = (unsigned int*)alloc((size_t)NBUCK * CAPB * 4);
  int* csrc   = (int*)alloc((size_t)NBUCK * CAPB * 4);
  uint2* rowptr2 = (uint2*)alloc((size_t)N * 8);
  unsigned short* EAb = (unsigned short*)alloc((size_t)E * 16 * 2);
  unsigned short* Hb = (unsigned short*)alloc((size_t)N * 64 * 2);
  unsigned short* A1 = (unsigned short*)alloc((size_t)N * 64 * 2);
  unsigned short* Yl = (unsigned short*)alloc((size_t)N * 64 * 2);
  unsigned short* Yr = (unsigned short*)alloc((size_t)N * 64 * 2);
  unsigned short* Gb = (unsigned short*)alloc((size_t)N * 64 * 2);
  unsigned short* W25T = (unsigned short*)alloc(64 * 64 * 2);
  unsigned short* We1T = (unsigned short*)alloc(64 * 32 * 2);
  unsigned short* Wo1T = (unsigned short*)alloc(64 * 64 * 2);
  unsigned short* WnL2T = (unsigned short*)alloc(64 * 128 * 2);
  float* cvec = (float*)alloc(64 * 4);
  (void)ws_size; (void)n_in; (void)out_size;

  k_flag<<<2, 256, 0, stream>>>(eidx, 8192, flag, gcursor);

  // MEGA1: decode+scatter + prep + WnL2T + layer-0 GEMM
  const int nDec = (E + 4095) / 4096;   // 245 decode+scatter blocks
  const int gB = (N + 63) / 64;
  const int nWork = 33 + gB;
  k_mega1<<<nDec + nWork, 256, 0, stream>>>(
      eidx, flag, E, nDec, nWork, gB,
      src, tgt, gcursor, tmp,
      x, Yl, Yr, N,
      We2, Wo1, be2, bo1, We1, Wl0, Wr0, Wl1, Wr1,
      W25T, We1T, Wo1T, cvec, WnL2T);

  // bsort (391 long-pole blocks first) + co-dispatched eattr conv
  const int nConv = (E * 4 + 1023) / 1024;   // 3907 conv blocks
  k_bsort<<<NBUCK + nConv, 256, 0, stream>>>(tmp, gcursor, csrc, rowptr2, N,
                                             NBUCK, (const float4*)eattr,
                                             (uint2*)EAb, E * 4);

  const int aggB = (N + 3) / 4;
  // agg0: H = relu(mean(Yl[src]) + bl0 + Yr)
  k_agg<false><<<aggB, 256, 0, stream>>>(Yl, rowptr2, csrc, bl0, Yr, Hb, N);
  // agg1': A1 = mean(H[src])  (raw mean; linearity moves Wl1 after the agg)
  k_agg<true><<<aggB, 256, 0, stream>>>(Hb, rowptr2, csrc, nullptr, nullptr,
                                        A1, N);
  // fused layer-2 + G: H2 = relu([A1|H]@[Wl1;Wr1]+bl1); G = H2@Wo1
  k_gemm2g<<<gB, 256, 0, stream>>>(A1, Hb, bl1, WnL2T, Wo1T, Gb, N);

  // MFMA edge pipeline v3
  const int nT = (E + 15) / 16;
  const int blocks = 3072;
  k_edge3<<<blocks, 256, 0, stream>>>(EAb, src, tgt, Gb, We1T, W25T, cvec,
                                      be1, Wo2, bo2, out, E, nT, blocks * 4);
}

// Round 12
// 372.675 us; speedup vs baseline: 1.0447x; 1.0118x over previous
//
#include <hip/hip_runtime.h>
#include <math.h>

typedef __attribute__((ext_vector_type(8))) short short8;
typedef __attribute__((ext_vector_type(4))) float f32x4;

#define CAPB 4096   // fixed capacity per coarse bucket (mean 2558, 30 sigma)

static __device__ __forceinline__ unsigned short f2bf(float f) {
  union { float f; unsigned int u; } x; x.f = f;
  unsigned int r = x.u + 0x7fffu + ((x.u >> 16) & 1u);  // RNE
  return (unsigned short)(r >> 16);
}
static __device__ __forceinline__ float bf2f(unsigned int u) {
  union { unsigned int u; float f; } x; x.u = u << 16; return x.f;
}

// ---------------------------------------------------------------------------
// Block 0: int64-vs-int32 edge_index detection. Block 1: zero gcursor[512].
__global__ void k_flag(const unsigned int* __restrict__ w, int nSample,
                       unsigned int* __restrict__ flag,
                       int* __restrict__ gcursor) {
  if (blockIdx.x == 1) {
    if (threadIdx.x < 256) { gcursor[threadIdx.x] = 0; gcursor[threadIdx.x + 256] = 0; }
    return;
  }
  if (blockIdx.x != 0) return;
  __shared__ unsigned int red[256];
  unsigned int v = 0;
  for (int i = threadIdx.x; i < nSample; i += 256) v |= w[2 * i + 1];
  red[threadIdx.x] = v;
  __syncthreads();
  for (int s = 128; s > 0; s >>= 1) {
    if (threadIdx.x < s) red[threadIdx.x] |= red[threadIdx.x + s];
    __syncthreads();
  }
  if (threadIdx.x == 0) flag[0] = red[0];  // nonzero => int32 layout
}

// ---------------------------------------------------------------------------
// MFMA node GEMM body. INLINEW: build B fragments directly from f32 W0/W1.
// MFMA layouts (gfx950, verified): A[m=lane&15][k=(lane>>4)*8+j],
// B[k][n=lane&15], C/D col=lane&15, row=(lane>>4)*4+reg.
template <int K, bool BF16IN, int NTILES, bool INLINEW>
__device__ __forceinline__ void ngemm_body(
    const void* __restrict__ Xv, const unsigned short* __restrict__ WnT,
    const float* __restrict__ W0f, const float* __restrict__ W1f,
    unsigned short* __restrict__ Y0, unsigned short* __restrict__ Y1,
    int N, int blk, unsigned short* __restrict__ sX) {
  constexpr int STR = K + 8;
  constexpr int NC = K / 32;
  const int tid = threadIdx.x;
  const int wv = tid >> 6, lane = tid & 63;
  const int m = lane & 15, q = lane >> 4;
  const int row0 = blk * 64;

  short8 bB[NTILES][NC];
#pragma unroll
  for (int ct = 0; ct < NTILES; ++ct)
#pragma unroll
    for (int c = 0; c < NC; ++c) {
      if constexpr (INLINEW) {
        int n = (NTILES == 2) ? (wv * 32 + ct * 16 + m) : (wv * 16 + m);
        const float* Wf = (n < 64) ? W0f : W1f;
        int nn = n & 63;
        union { short8 s; unsigned short h[8]; } ub;
#pragma unroll
        for (int j = 0; j < 8; ++j)
          ub.h[j] = f2bf(Wf[(size_t)(c * 32 + q * 8 + j) * 64 + nn]);
        bB[ct][c] = ub.s;
      } else {
        int n = (NTILES == 2) ? (wv * 32 + ct * 16 + m) : (wv * 16 + m);
        bB[ct][c] = *(const short8*)(WnT + (size_t)n * K + c * 32 + q * 8);
      }
    }

#pragma unroll
  for (int i = 0; i < K / 16; ++i) {
    int f = tid + 256 * i;
    int r = f / (K / 4);
    int c4 = f % (K / 4);
    int rr = row0 + r; if (rr >= N) rr = N - 1;
    uint2 pk;
    if constexpr (BF16IN) {
      pk = *(const uint2*)((const unsigned short*)Xv + (size_t)rr * K + c4 * 4);
    } else {
      float4 v = *(const float4*)((const float*)Xv + (size_t)rr * K + c4 * 4);
      pk.x = (unsigned int)f2bf(v.x) | ((unsigned int)f2bf(v.y) << 16);
      pk.y = (unsigned int)f2bf(v.z) | ((unsigned int)f2bf(v.w) << 16);
    }
    *(uint2*)(sX + r * STR + c4 * 4) = pk;
  }
  __syncthreads();

  f32x4 acc[4][NTILES];
#pragma unroll
  for (int rt = 0; rt < 4; ++rt)
#pragma unroll
    for (int ct = 0; ct < NTILES; ++ct)
#pragma unroll
      for (int r = 0; r < 4; ++r) acc[rt][ct][r] = 0.f;

#pragma unroll
  for (int c = 0; c < NC; ++c) {
    short8 a[4];
#pragma unroll
    for (int rt = 0; rt < 4; ++rt)
      a[rt] = *(const short8*)(sX + (rt * 16 + m) * STR + c * 32 + q * 8);
#pragma unroll
    for (int rt = 0; rt < 4; ++rt)
#pragma unroll
      for (int ct = 0; ct < NTILES; ++ct)
        acc[rt][ct] = __builtin_amdgcn_mfma_f32_16x16x32_bf16(a[rt], bB[ct][c], acc[rt][ct], 0, 0, 0);
  }

#pragma unroll
  for (int rt = 0; rt < 4; ++rt)
#pragma unroll
    for (int ct = 0; ct < NTILES; ++ct) {
      unsigned short* Yw;
      int n;
      if constexpr (NTILES == 2) {
        Yw = (wv < 2) ? Y0 : Y1;
        n = (wv & 1) * 32 + ct * 16 + m;
      } else {
        Yw = Y0;
        n = wv * 16 + m;
      }
#pragma unroll
      for (int reg = 0; reg < 4; ++reg) {
        int row = row0 + rt * 16 + q * 4 + reg;
        if (row < N) Yw[(size_t)row * 64 + n] = f2bf(acc[rt][ct][reg]);
      }
    }
}

// ---------------------------------------------------------------------------
// MEGA1: decode+bucket-scatter + prep + WnL2T + layer-0 GEMM (INLINEW).
// Proportional striping so decode blocks co-reside with compute from t=0.
__global__ __launch_bounds__(256) void k_mega1(
    const unsigned int* __restrict__ w, const unsigned int* __restrict__ flag,
    int E, int nDec, int nWork, int gB,
    int* __restrict__ src, int* __restrict__ tgt,
    int* __restrict__ gcursor, unsigned int* __restrict__ tmp,
    const float* __restrict__ x, unsigned short* __restrict__ Yl,
    unsigned short* __restrict__ Yr, int N,
    const float* __restrict__ We2, const float* __restrict__ Wo1,
    const float* __restrict__ be2, const float* __restrict__ bo1,
    const float* __restrict__ We1,
    const float* __restrict__ Wl0, const float* __restrict__ Wr0,
    const float* __restrict__ Wl1, const float* __restrict__ Wr1,
    unsigned short* __restrict__ W25T, unsigned short* __restrict__ We1T,
    unsigned short* __restrict__ Wo1T, float* __restrict__ cvec,
    unsigned short* __restrict__ WnL2T) {
  __shared__ __align__(16) char smem[64 * 136 * 2];   // 17408 B, union use
  const int tid = threadIdx.x;
  const int tot = nDec + nWork;
  const int di  = (int)(((long long)blockIdx.x * nDec) / tot);
  const int di1 = (int)(((long long)(blockIdx.x + 1) * nDec) / tot);

  if (di1 > di) {
    // ---- decode+scatter block #di: edges [di*4096, min(E, +4096))
    int* hist = (int*)smem;   // 512 ints
    hist[tid] = 0; hist[tid + 256] = 0;
    __syncthreads();
    const int e0 = di * 4096;
    const int e1 = (e0 + 4096 < E) ? (e0 + 4096) : E;
    const unsigned int fl = flag[0];
    for (int e = e0 + tid; e < e1; e += 256) {
      int s, t;
      if (fl) { s = (int)w[e]; t = (int)w[E + e]; }
      else    { s = (int)w[2 * e]; t = (int)w[2 * (E + e)]; }
      src[e] = s; tgt[e] = t;
      atomicAdd(hist + (t >> 8), 1);
    }
    __syncthreads();
    {
      int c0 = hist[tid], c1 = hist[tid + 256];
      int s0 = (c0 > 0) ? atomicAdd(gcursor + tid, c0) : 0;
      int s1 = (c1 > 0) ? atomicAdd(gcursor + tid + 256, c1) : 0;
      __syncthreads();
      hist[tid] = s0; hist[tid + 256] = s1;
    }
    __syncthreads();
    for (int e = e0 + tid; e < e1; e += 256) {
      int s, t;
      if (fl) { s = (int)w[e]; t = (int)w[E + e]; }
      else    { s = (int)w[2 * e]; t = (int)w[2 * (E + e)]; }
      int b = t >> 8;
      int pos = atomicAdd(hist + b, 1);
      if (pos < CAPB)
        tmp[(size_t)b * CAPB + pos] = ((unsigned int)s << 8) | (unsigned int)(t & 255);
    }
    return;
  }
  const int wi = blockIdx.x - di;
  if (wi == 0) {
    // ---- prep: W25T=(We2@Wo1)^T, Wo1T, We1T, cvec (Wo1 staged in smem)
    float* sB = (float*)smem;
    for (int i = tid; i < 1024; i += 256)
      *(float4*)&sB[i * 4] = *(const float4*)(Wo1 + i * 4);
    __syncthreads();
    for (int idx = tid; idx < 4096; idx += 256) {
      int k = idx >> 6, n = idx & 63;   // k wave-uniform -> We2 scalarizes
      float s = 0.f;
#pragma unroll 8
      for (int mm = 0; mm < 64; ++mm) s = fmaf(We2[k * 64 + mm], sB[mm * 64 + n], s);
      W25T[n * 64 + k] = f2bf(s);
      Wo1T[n * 64 + k] = f2bf(sB[k * 64 + n]);
    }
    for (int idx = tid; idx < 2048; idx += 256) {
      int n = idx >> 5, k = idx & 31;
      We1T[n * 32 + k] = (k < 16) ? f2bf(We1[k * 64 + n]) : (unsigned short)0;
    }
    if (tid < 64) {
      float s = bo1[tid];
#pragma unroll 8
      for (int mm = 0; mm < 64; ++mm) s = fmaf(be2[mm], sB[mm * 64 + tid], s);
      cvec[tid] = s;
    }
  } else if (wi <= 32) {
    // ---- WnL2T: [64 n][128 k], k<64 from Wl1, k>=64 from Wr1 (stacked K)
    int idx = (wi - 1) * 256 + tid;   // 0..8191
    int n = idx >> 7, k = idx & 127;
    float v = (k < 64) ? Wl1[(size_t)k * 64 + n]
                       : Wr1[(size_t)(k - 64) * 64 + n];
    WnL2T[idx] = f2bf(v);
  } else {
    // ---- layer-0 GEMM (inline f32 weights)
    ngemm_body<128, false, 2, true>(x, nullptr, Wl0, Wr0, Yl, Yr, N,
                                    wi - 33, (unsigned short*)smem);
  }
}

// ---------------------------------------------------------------------------
// Per-bucket counting sort + co-dispatched eattr conv (r8 form).
__global__ __launch_bounds__(256) void k_bsort(
    const unsigned int* __restrict__ tmp, const int* __restrict__ gcursor,
    int* __restrict__ csrc, uint2* __restrict__ rowptr2, int N, int nBuck,
    const float4* __restrict__ ef, uint2* __restrict__ eb, int nItems) {
  __shared__ int cnt[256];
  __shared__ int curs[256];
  __shared__ int wsum[4];
  const int tid = threadIdx.x;
  if (blockIdx.x >= nBuck) {
    const int ci = blockIdx.x - nBuck;
#pragma unroll
    for (int j = 0; j < 4; ++j) {
      int i = ci * 1024 + j * 256 + tid;
      if (i < nItems) {
        float4 v = ef[i];
        uint2 pk;
        pk.x = (unsigned int)f2bf(v.x) | ((unsigned int)f2bf(v.y) << 16);
        pk.y = (unsigned int)f2bf(v.z) | ((unsigned int)f2bf(v.w) << 16);
        eb[i] = pk;
      }
    }
    return;
  }
  const int b = blockIdx.x;
  int c = gcursor[b]; if (c > CAPB) c = CAPB;
  cnt[tid] = 0;
  __syncthreads();
  const unsigned int* reg = tmp + (size_t)b * CAPB;
  for (int i = tid; i < c; i += 256) atomicAdd(&cnt[reg[i] & 255u], 1);
  __syncthreads();
  const int lane = tid & 63, wv = tid >> 6;
  int v = cnt[tid];
  int incl = v;
#pragma unroll
  for (int off = 1; off < 64; off <<= 1) {
    int t = __shfl_up(incl, off, 64);
    if (lane >= off) incl += t;
  }
  if (lane == 63) wsum[wv] = incl;
  __syncthreads();
  int add = 0;
  for (int ww = 0; ww < wv; ++ww) add += wsum[ww];
  int excl = add + incl - v;
  curs[tid] = excl;
  int node = b * 256 + tid;
  if (node < N)
    rowptr2[node] = make_uint2((unsigned int)(b * CAPB + excl),
                               (unsigned int)(b * CAPB + excl + v));
  __syncthreads();
  for (int i = tid; i < c; i += 256) {
    unsigned int wd = reg[i];
    int p = atomicAdd(&curs[wd & 255u], 1);
    csrc[(size_t)b * CAPB + p] = (int)(wd >> 8);
  }
}

// ---------------------------------------------------------------------------
// CSR aggregate v3 (r11 proven): 8 edge-slots x 8 col-octs, uint4 loads.
// RAW=false: H = relu(sum/deg + bias + Yr). RAW=true: A = sum/deg.
template <bool RAW>
__global__ __launch_bounds__(256) void k_agg(
    const unsigned short* __restrict__ Y, const uint2* __restrict__ rowptr2,
    const int* __restrict__ csrc, const float* __restrict__ bias,
    const unsigned short* __restrict__ Yr, unsigned short* __restrict__ H,
    int N) {
  int node = (blockIdx.x * 256 + threadIdx.x) >> 6;
  if (node >= N) return;
  const int lane = threadIdx.x & 63;
  const int c8 = lane & 7;    // col-oct: cols [c8*8, c8*8+8)
  const int rr = lane >> 3;   // 8 edge slots
  uint2 be = rowptr2[node];
  int beg = (int)be.x, end = (int)be.y;
  float a0 = 0.f, a1 = 0.f, a2 = 0.f, a3 = 0.f;
  float a4 = 0.f, a5 = 0.f, a6 = 0.f, a7 = 0.f;
  float b0 = 0.f, b1 = 0.f, b2 = 0.f, b3 = 0.f;
  float b4 = 0.f, b5 = 0.f, b6 = 0.f, b7 = 0.f;
  for (int e = beg; e < end; e += 16) {
    int e0 = e + rr, e1 = e + 8 + rr;
    bool p0 = e0 < end, p1 = e1 < end;
    int s0 = p0 ? csrc[e0] : 0;
    int s1 = p1 ? csrc[e1] : 0;
    uint4 v0, v1;
    if (p0) v0 = *(const uint4*)(Y + (size_t)s0 * 64 + c8 * 8);
    if (p1) v1 = *(const uint4*)(Y + (size_t)s1 * 64 + c8 * 8);
    if (p0) {
      a0 += bf2f(v0.x & 0xffffu); a1 += bf2f(v0.x >> 16);
      a2 += bf2f(v0.y & 0xffffu); a3 += bf2f(v0.y >> 16);
      a4 += bf2f(v0.z & 0xffffu); a5 += bf2f(v0.z >> 16);
      a6 += bf2f(v0.w & 0xffffu); a7 += bf2f(v0.w >> 16);
    }
    if (p1) {
      b0 += bf2f(v1.x & 0xffffu); b1 += bf2f(v1.x >> 16);
      b2 += bf2f(v1.y & 0xffffu); b3 += bf2f(v1.y >> 16);
      b4 += bf2f(v1.z & 0xffffu); b5 += bf2f(v1.z >> 16);
      b6 += bf2f(v1.w & 0xffffu); b7 += bf2f(v1.w >> 16);
    }
  }
  a0 += b0; a1 += b1; a2 += b2; a3 += b3;
  a4 += b4; a5 += b5; a6 += b6; a7 += b7;
#pragma unroll
  for (int msk = 8; msk <= 32; msk <<= 1) {
    a0 += __shfl_xor(a0, msk, 64);
    a1 += __shfl_xor(a1, msk, 64);
    a2 += __shfl_xor(a2, msk, 64);
    a3 += __shfl_xor(a3, msk, 64);
    a4 += __shfl_xor(a4, msk, 64);
    a5 += __shfl_xor(a5, msk, 64);
    a6 += __shfl_xor(a6, msk, 64);
    a7 += __shfl_xor(a7, msk, 64);
  }
  if (rr == 0) {
    float cdeg = (float)(end - beg);
    if (cdeg < 1.f) cdeg = 1.f;
    float inv = 1.f / cdeg;
    float o0, o1, o2, o3, o4, o5, o6, o7;
    if constexpr (RAW) {
      o0 = a0 * inv; o1 = a1 * inv; o2 = a2 * inv; o3 = a3 * inv;
      o4 = a4 * inv; o5 = a5 * inv; o6 = a6 * inv; o7 = a7 * inv;
    } else {
      float4 bv0 = *(const float4*)(bias + c8 * 8);
      float4 bv1 = *(const float4*)(bias + c8 * 8 + 4);
      uint4 yv = *(const uint4*)(Yr + (size_t)node * 64 + c8 * 8);
      o0 = fmaxf(a0 * inv + bv0.x + bf2f(yv.x & 0xffffu), 0.f);
      o1 = fmaxf(a1 * inv + bv0.y + bf2f(yv.x >> 16), 0.f);
      o2 = fmaxf(a2 * inv + bv0.z + bf2f(yv.y & 0xffffu), 0.f);
      o3 = fmaxf(a3 * inv + bv0.w + bf2f(yv.y >> 16), 0.f);
      o4 = fmaxf(a4 * inv + bv1.x + bf2f(yv.z & 0xffffu), 0.f);
      o5 = fmaxf(a5 * inv + bv1.y + bf2f(yv.z >> 16), 0.f);
      o6 = fmaxf(a6 * inv + bv1.z + bf2f(yv.w & 0xffffu), 0.f);
      o7 = fmaxf(a7 * inv + bv1.w + bf2f(yv.w >> 16), 0.f);
    }
    uint4 pk;
    pk.x = (unsigned int)f2bf(o0) | ((unsigned int)f2bf(o1) << 16);
    pk.y = (unsigned int)f2bf(o2) | ((unsigned int)f2bf(o3) << 16);
    pk.z = (unsigned int)f2bf(o4) | ((unsigned int)f2bf(o5) << 16);
    pk.w = (unsigned int)f2bf(o6) | ((unsigned int)f2bf(o7) << 16);
    *(uint4*)(H + (size_t)node * 64 + c8 * 8) = pk;
  }
}

// ---------------------------------------------------------------------------
// FUSED layer-2 + G GEMM (r9 form): H2 = relu([A1|H] @ [Wl1;Wr1] + bl1) in
// registers (K=128 MFMA), LDS, then G = H2 @ Wo1 (K=64 MFMA).
__global__ __launch_bounds__(256) void k_gemm2g(
    const unsigned short* __restrict__ A1, const unsigned short* __restrict__ H,
    const float* __restrict__ bl1, const unsigned short* __restrict__ WnL2T,
    const unsigned short* __restrict__ Wo1T, unsigned short* __restrict__ Gb,
    int N) {
  __shared__ __align__(16) unsigned short sX[64 * 136];
  __shared__ __align__(16) unsigned short sH2[64 * 72];
  const int tid = threadIdx.x;
  const int wv = tid >> 6, lane = tid & 63;
  const int m = lane & 15, q = lane >> 4;
  const int row0 = blockIdx.x * 64;
  const int n = wv * 16 + m;

  short8 bB1[4], bB2[2];
#pragma unroll
  for (int c = 0; c < 4; ++c)
    bB1[c] = *(const short8*)(WnL2T + (size_t)n * 128 + c * 32 + q * 8);
#pragma unroll
  for (int c = 0; c < 2; ++c)
    bB2[c] = *(const short8*)(Wo1T + (size_t)n * 64 + c * 32 + q * 8);
  const float bl = bl1[n];

  // stage [A1|H]: 64 rows x 128 bf16 cols; cols 0-63 = A1, 64-127 = H
#pragma unroll
  for (int i = 0; i < 8; ++i) {
    int f = tid + 256 * i;        // 2048 uint2 quads
    int r = f >> 5;               // 32 quads per row
    int c4 = f & 31;
    int rr = row0 + r; if (rr >= N) rr = N - 1;
    uint2 pk;
    if (c4 < 16) pk = *(const uint2*)(A1 + (size_t)rr * 64 + c4 * 4);
    else         pk = *(const uint2*)(H  + (size_t)rr * 64 + (c4 - 16) * 4);
    *(uint2*)(sX + r * 136 + c4 * 4) = pk;
  }
  __syncthreads();

  // stage 1: K=128 MFMA -> H2
  f32x4 acc[4];
#pragma unroll
  for (int rt = 0; rt < 4; ++rt)
#pragma unroll
    for (int r = 0; r < 4; ++r) acc[rt][r] = 0.f;
#pragma unroll
  for (int c = 0; c < 4; ++c)
#pragma unroll
    for (int rt = 0; rt < 4; ++rt) {
      short8 a = *(const short8*)(sX + (rt * 16 + m) * 136 + c * 32 + q * 8);
      acc[rt] = __builtin_amdgcn_mfma_f32_16x16x32_bf16(a, bB1[c], acc[rt], 0, 0, 0);
    }

  // H2 = relu(acc + bl1) -> LDS (A-frag layout, stride 72)
#pragma unroll
  for (int rt = 0; rt < 4; ++rt)
#pragma unroll
    for (int reg = 0; reg < 4; ++reg)
      sH2[(rt * 16 + q * 4 + reg) * 72 + n] = f2bf(fmaxf(acc[rt][reg] + bl, 0.f));
  __syncthreads();

  // stage 2: K=64 MFMA -> G
  f32x4 acc2[4];
#pragma unroll
  for (int rt = 0; rt < 4; ++rt)
#pragma unroll
    for (int r = 0; r < 4; ++r) acc2[rt][r] = 0.f;
#pragma unroll
  for (int c = 0; c < 2; ++c)
#pragma unroll
    for (int rt = 0; rt < 4; ++rt) {
      short8 a = *(const short8*)(sH2 + (rt * 16 + m) * 72 + c * 32 + q * 8);
      acc2[rt] = __builtin_amdgcn_mfma_f32_16x16x32_bf16(a, bB2[c], acc2[rt], 0, 0, 0);
    }

#pragma unroll
  for (int rt = 0; rt < 4; ++rt)
#pragma unroll
    for (int reg = 0; reg < 4; ++reg) {
      int row = row0 + rt * 16 + q * 4 + reg;
      if (row < N) Gb[(size_t)row * 64 + n] = f2bf(acc2[rt][reg]);
    }
}

// ---------------------------------------------------------------------------
// MFMA edge pipeline v5: Gb gathers request-halved (uint4, 8 lanes/row)
// per r11's confirmed request-rate model. Lane layout for the gather phase:
// s8 = lane>>3 (edge slot), c8 = lane&7 (col oct). Per tile: 2 rounds x
// {src,tgt} uint4 loads = 4 loads/lane (was 8 x uint2), 4 shfls (was 8).
// sT1 path, MFMA structure, output path unchanged from v3.
#define T1_STRIDE 72
#define G_STRIDE 68
__global__ __launch_bounds__(256) void k_edge3(
    const unsigned short* __restrict__ EAb, const int* __restrict__ src,
    const int* __restrict__ tgt, const unsigned short* __restrict__ Gb,
    const unsigned short* __restrict__ We1T,
    const unsigned short* __restrict__ W25T,
    const float* __restrict__ cvec, const float* __restrict__ be1,
    const float* __restrict__ Wo2, const float* __restrict__ bo2,
    float* __restrict__ out, int E, int nT, int nWaves) {
  __shared__ unsigned short sT1a[4][16 * T1_STRIDE];
  __shared__ float sGa[4][16 * G_STRIDE];
  const int tid = threadIdx.x;
  const int wid = tid >> 6, lane = tid & 63;
  const int m = lane & 15, q = lane >> 4;
  const int c8 = lane & 7, s8 = lane >> 3;
  unsigned short* sT1 = sT1a[wid];
  float* sG = sGa[wid];

  short8 bWe1[4], bW25[4][2];
  float cv[4], wo2v[4], be1v[4];
#pragma unroll
  for (int nt = 0; nt < 4; ++nt) {
    int n = nt * 16 + m;
    bWe1[nt] = *(const short8*)(We1T + n * 32 + q * 8);
    bW25[nt][0] = *(const short8*)(W25T + n * 64 + q * 8);
    bW25[nt][1] = *(const short8*)(W25T + n * 64 + 32 + q * 8);
    cv[nt] = cvec[n];
    wo2v[nt] = Wo2[n];
    be1v[nt] = be1[n];
  }
  const float b_out = bo2[0];
  const short8 zfrag = {};

  int t = blockIdx.x * 4 + wid;
  if (t >= nT) return;
  int il = t * 16 + m; if (il >= E) il = E - 1;
  int my_idx = (lane < 16) ? src[il] : ((lane < 32) ? tgt[il] : 0);

  while (true) {
    const int base = t * 16;
    const int tn = t + nWaves;
    const bool last = (tn >= nT);
    const int tc = last ? t : tn;

    int il_n = tc * 16 + m; if (il_n >= E) il_n = E - 1;
    int idx_n = (lane < 16) ? src[il_n] : ((lane < 32) ? tgt[il_n] : 0);

    // ---- Gb gathers: 2 edge-slots x {src,tgt}, uint4 per lane
    uint4 sv[2], tv[2];
#pragma unroll
    for (int j = 0; j < 2; ++j) {
      int es = s8 + 8 * j;
      int a = __shfl(my_idx, es, 64);
      int b = __shfl(my_idx, 16 + es, 64);
      sv[j] = *(const uint4*)(Gb + (size_t)a * 64 + c8 * 8);
      tv[j] = *(const uint4*)(Gb + (size_t)b * 64 + c8 * 8);
    }

    int er = base + m; if (er >= E) er = E - 1;
    short8 aEA = zfrag;
    if (q < 2) aEA = *(const short8*)(EAb + (size_t)er * 16 + (q & 1) * 8);

    f32x4 t1[4];
#pragma unroll
    for (int nt = 0; nt < 4; ++nt) {
      f32x4 cinit; cinit[0] = be1v[nt]; cinit[1] = be1v[nt];
      cinit[2] = be1v[nt]; cinit[3] = be1v[nt];
      t1[nt] = __builtin_amdgcn_mfma_f32_16x16x32_bf16(aEA, bWe1[nt], cinit, 0, 0, 0);
    }
#pragma unroll
    for (int nt = 0; nt < 4; ++nt)
#pragma unroll
      for (int r = 0; r < 4; ++r)
        sT1[(q * 4 + r) * T1_STRIDE + nt * 16 + m] = f2bf(fmaxf(t1[nt][r], 0.f));
    short8 aT0 = *(short8*)(sT1 + m * T1_STRIDE + q * 8);
    short8 aT1 = *(short8*)(sT1 + m * T1_STRIDE + 32 + q * 8);

    // ---- g = Gb[src]+Gb[tgt] -> sG (per-wave slice, wave-synchronous)
#pragma unroll
    for (int j = 0; j < 2; ++j) {
      int es = s8 + 8 * j;
      f32x4 g0, g1;
      g0[0] = bf2f(sv[j].x & 0xffffu) + bf2f(tv[j].x & 0xffffu);
      g0[1] = bf2f(sv[j].x >> 16)     + bf2f(tv[j].x >> 16);
      g0[2] = bf2f(sv[j].y & 0xffffu) + bf2f(tv[j].y & 0xffffu);
      g0[3] = bf2f(sv[j].y >> 16)     + bf2f(tv[j].y >> 16);
      g1[0] = bf2f(sv[j].z & 0xffffu) + bf2f(tv[j].z & 0xffffu);
      g1[1] = bf2f(sv[j].z >> 16)     + bf2f(tv[j].z >> 16);
      g1[2] = bf2f(sv[j].w & 0xffffu) + bf2f(tv[j].w & 0xffffu);
      g1[3] = bf2f(sv[j].w >> 16)     + bf2f(tv[j].w >> 16);
      *(f32x4*)(sG + es * G_STRIDE + c8 * 8) = g0;
      *(f32x4*)(sG + es * G_STRIDE + c8 * 8 + 4) = g1;
    }

    f32x4 acc[4];
#pragma unroll
    for (int nt = 0; nt < 4; ++nt)
#pragma unroll
      for (int r = 0; r < 4; ++r)
        acc[nt][r] = cv[nt] + sG[(q * 4 + r) * G_STRIDE + nt * 16 + m];
#pragma unroll
    for (int nt = 0; nt < 4; ++nt) {
      acc[nt] = __builtin_amdgcn_mfma_f32_16x16x32_bf16(aT0, bW25[nt][0], acc[nt], 0, 0, 0);
      acc[nt] = __builtin_amdgcn_mfma_f32_16x16x32_bf16(aT1, bW25[nt][1], acc[nt], 0, 0, 0);
    }

    float p[4];
#pragma unroll
    for (int r = 0; r < 4; ++r) {
      p[r] = fmaxf(acc[0][r], 0.f) * wo2v[0] + fmaxf(acc[1][r], 0.f) * wo2v[1] +
             fmaxf(acc[2][r], 0.f) * wo2v[2] + fmaxf(acc[3][r], 0.f) * wo2v[3];
    }
#pragma unroll
    for (int msk = 1; msk <= 8; msk <<= 1) {
#pragma unroll
      for (int r = 0; r < 4; ++r) p[r] += __shfl_xor(p[r], msk, 64);
    }
    if (m == 0) {
#pragma unroll
      for (int r = 0; r < 4; ++r) {
        int row = base + q * 4 + r;
        if (row < E) out[row] = 1.f / (1.f + __expf(-(p[r] + b_out)));
      }
    }

    if (last) break;
    t = tn; my_idx = idx_n;
  }
}

// ---------------------------------------------------------------------------
extern "C" void kernel_launch(void* const* d_in, const int* in_sizes, int n_in,
                              void* d_out, int out_size, void* d_ws, size_t ws_size,
                              hipStream_t stream) {
  const float* x     = (const float*)d_in[0];
  const unsigned int* eidx = (const unsigned int*)d_in[1];
  const float* eattr = (const float*)d_in[2];
  const float* We1 = (const float*)d_in[3];
  const float* be1 = (const float*)d_in[4];
  const float* We2 = (const float*)d_in[5];
  const float* be2 = (const float*)d_in[6];
  const float* Wl0 = (const float*)d_in[7];
  const float* bl0 = (const float*)d_in[8];
  const float* Wr0 = (const float*)d_in[9];
  const float* Wl1 = (const float*)d_in[10];
  const float* bl1 = (const float*)d_in[11];
  const float* Wr1 = (const float*)d_in[12];
  const float* Wo1 = (const float*)d_in[13];
  const float* bo1 = (const float*)d_in[14];
  const float* Wo2 = (const float*)d_in[15];
  const float* bo2 = (const float*)d_in[16];

  const int N = in_sizes[0] / 128;   // 100000
  const int E = in_sizes[2] / 16;    // 1000000
  const int NBUCK = (N + 255) >> 8;  // 391 coarse buckets (tgt>>8)
  float* out = (float*)d_out;

  char* ws = (char*)d_ws;
  size_t off = 0;
  auto alloc = [&](size_t bytes) {
    char* p = ws + off;
    off += (bytes + 255) & ~(size_t)255;
    return p;
  };
  unsigned int* flag = (unsigned int*)alloc(256);
  int* src    = (int*)alloc((size_t)E * 4);
  int* tgt    = (int*)alloc((size_t)E * 4);
  int* gcursor = (int*)alloc(512 * 4);
  unsigned int* tmp = (unsigned int*)alloc((size_t)NBUCK * CAPB * 4);
  int* csrc   = (int*)alloc((size_t)NBUCK * CAPB * 4);
  uint2* rowptr2 = (uint2*)alloc((size_t)N * 8);
  unsigned short* EAb = (unsigned short*)alloc((size_t)E * 16 * 2);
  unsigned short* Hb = (unsigned short*)alloc((size_t)N * 64 * 2);
  unsigned short* A1 = (unsigned short*)alloc((size_t)N * 64 * 2);
  unsigned short* Yl = (unsigned short*)alloc((size_t)N * 64 * 2);
  unsigned short* Yr = (unsigned short*)alloc((size_t)N * 64 * 2);
  unsigned short* Gb = (unsigned short*)alloc((size_t)N * 64 * 2);
  unsigned short* W25T = (unsigned short*)alloc(64 * 64 * 2);
  unsigned short* We1T = (unsigned short*)alloc(64 * 32 * 2);
  unsigned short* Wo1T = (unsigned short*)alloc(64 * 64 * 2);
  unsigned short* WnL2T = (unsigned short*)alloc(64 * 128 * 2);
  float* cvec = (float*)alloc(64 * 4);
  (void)ws_size; (void)n_in; (void)out_size;

  k_flag<<<2, 256, 0, stream>>>(eidx, 8192, flag, gcursor);

  // MEGA1: decode+scatter + prep + WnL2T + layer-0 GEMM
  const int nDec = (E + 4095) / 4096;   // 245 decode+scatter blocks
  const int gB = (N + 63) / 64;
  const int nWork = 33 + gB;
  k_mega1<<<nDec + nWork, 256, 0, stream>>>(
      eidx, flag, E, nDec, nWork, gB,
      src, tgt, gcursor, tmp,
      x, Yl, Yr, N,
      We2, Wo1, be2, bo1, We1, Wl0, Wr0, Wl1, Wr1,
      W25T, We1T, Wo1T, cvec, WnL2T);

  // bsort (391 long-pole blocks first) + co-dispatched eattr conv
  const int nConv = (E * 4 + 1023) / 1024;   // 3907 conv blocks
  k_bsort<<<NBUCK + nConv, 256, 0, stream>>>(tmp, gcursor, csrc, rowptr2, N,
                                             NBUCK, (const float4*)eattr,
                                             (uint2*)EAb, E * 4);

  const int aggB = (N + 3) / 4;
  // agg0: H = relu(mean(Yl[src]) + bl0 + Yr)
  k_agg<false><<<aggB, 256, 0, stream>>>(Yl, rowptr2, csrc, bl0, Yr, Hb, N);
  // agg1': A1 = mean(H[src])  (raw mean; linearity moves Wl1 after the agg)
  k_agg<true><<<aggB, 256, 0, stream>>>(Hb, rowptr2, csrc, nullptr, nullptr,
                                        A1, N);
  // fused layer-2 + G: H2 = relu([A1|H]@[Wl1;Wr1]+bl1); G = H2@Wo1
  k_gemm2g<<<gB, 256, 0, stream>>>(A1, Hb, bl1, WnL2T, Wo1T, Gb, N);

  // MFMA edge pipeline v5
  const int nT = (E + 15) / 16;
  const int blocks = 3072;
  k_edge3<<<blocks, 256, 0, stream>>>(EAb, src, tgt, Gb, We1T, W25T, cvec,
                                      be1, Wo2, bo2, out, E, nT, blocks * 4);
}

// Round 13
// 369.201 us; speedup vs baseline: 1.0545x; 1.0094x over previous
//
#include <hip/hip_runtime.h>
#include <math.h>

typedef __attribute__((ext_vector_type(8))) short short8;
typedef __attribute__((ext_vector_type(4))) float f32x4;

#define CAPB 4096   // fixed capacity per coarse bucket (mean 2558, 30 sigma)

static __device__ __forceinline__ unsigned short f2bf(float f) {
  union { float f; unsigned int u; } x; x.f = f;
  unsigned int r = x.u + 0x7fffu + ((x.u >> 16) & 1u);  // RNE
  return (unsigned short)(r >> 16);
}
static __device__ __forceinline__ float bf2f(unsigned int u) {
  union { unsigned int u; float f; } x; x.u = u << 16; return x.f;
}

// ---------------------------------------------------------------------------
// Block 0: int64-vs-int32 detection. Block 1: zero gcursor[512].
// Blocks 2..65: WnT0 transpose (128n x 128k; n<64 Wl0 else Wr0) -- prepared
// HERE so mega1's 1563 gemm blocks read clean b128 fragments instead of each
// re-converting f32 weights (64 scalar loads + 64 f2bf per lane per block).
__global__ void k_flag(const unsigned int* __restrict__ w, int nSample,
                       unsigned int* __restrict__ flag,
                       int* __restrict__ gcursor,
                       const float* __restrict__ Wl0,
                       const float* __restrict__ Wr0,
                       unsigned short* __restrict__ WnT0) {
  const int b = blockIdx.x, tid = threadIdx.x;
  if (b >= 2) {
    int idx = (b - 2) * 256 + tid;    // 0..16383
    int n = idx >> 7, k = idx & 127;
    float v = (n < 64) ? Wl0[(size_t)k * 64 + n] : Wr0[(size_t)k * 64 + (n - 64)];
    WnT0[idx] = f2bf(v);
    return;
  }
  if (b == 1) {
    gcursor[tid] = 0; gcursor[tid + 256] = 0;
    return;
  }
  __shared__ unsigned int red[256];
  unsigned int v = 0;
  for (int i = tid; i < nSample; i += 256) v |= w[2 * i + 1];
  red[tid] = v;
  __syncthreads();
  for (int s = 128; s > 0; s >>= 1) {
    if (tid < s) red[tid] |= red[tid + s];
    __syncthreads();
  }
  if (tid == 0) flag[0] = red[0];  // nonzero => int32 layout
}

// ---------------------------------------------------------------------------
// MFMA node GEMM body (WnT path). MFMA layouts (gfx950, verified):
// A[m=lane&15][k=(lane>>4)*8+j], B[k][n=lane&15], C/D col=lane&15,
// row=(lane>>4)*4+reg.
template <int K, bool BF16IN, int NTILES>
__device__ __forceinline__ void ngemm_body(
    const void* __restrict__ Xv, const unsigned short* __restrict__ WnT,
    unsigned short* __restrict__ Y0, unsigned short* __restrict__ Y1,
    int N, int blk, unsigned short* __restrict__ sX) {
  constexpr int STR = K + 8;
  constexpr int NC = K / 32;
  const int tid = threadIdx.x;
  const int wv = tid >> 6, lane = tid & 63;
  const int m = lane & 15, q = lane >> 4;
  const int row0 = blk * 64;

  short8 bB[NTILES][NC];
#pragma unroll
  for (int ct = 0; ct < NTILES; ++ct)
#pragma unroll
    for (int c = 0; c < NC; ++c) {
      int n = (NTILES == 2) ? (wv * 32 + ct * 16 + m) : (wv * 16 + m);
      bB[ct][c] = *(const short8*)(WnT + (size_t)n * K + c * 32 + q * 8);
    }

#pragma unroll
  for (int i = 0; i < K / 16; ++i) {
    int f = tid + 256 * i;
    int r = f / (K / 4);
    int c4 = f % (K / 4);
    int rr = row0 + r; if (rr >= N) rr = N - 1;
    uint2 pk;
    if constexpr (BF16IN) {
      pk = *(const uint2*)((const unsigned short*)Xv + (size_t)rr * K + c4 * 4);
    } else {
      float4 v = *(const float4*)((const float*)Xv + (size_t)rr * K + c4 * 4);
      pk.x = (unsigned int)f2bf(v.x) | ((unsigned int)f2bf(v.y) << 16);
      pk.y = (unsigned int)f2bf(v.z) | ((unsigned int)f2bf(v.w) << 16);
    }
    *(uint2*)(sX + r * STR + c4 * 4) = pk;
  }
  __syncthreads();

  f32x4 acc[4][NTILES];
#pragma unroll
  for (int rt = 0; rt < 4; ++rt)
#pragma unroll
    for (int ct = 0; ct < NTILES; ++ct)
#pragma unroll
      for (int r = 0; r < 4; ++r) acc[rt][ct][r] = 0.f;

#pragma unroll
  for (int c = 0; c < NC; ++c) {
    short8 a[4];
#pragma unroll
    for (int rt = 0; rt < 4; ++rt)
      a[rt] = *(const short8*)(sX + (rt * 16 + m) * STR + c * 32 + q * 8);
#pragma unroll
    for (int rt = 0; rt < 4; ++rt)
#pragma unroll
      for (int ct = 0; ct < NTILES; ++ct)
        acc[rt][ct] = __builtin_amdgcn_mfma_f32_16x16x32_bf16(a[rt], bB[ct][c], acc[rt][ct], 0, 0, 0);
  }

#pragma unroll
  for (int rt = 0; rt < 4; ++rt)
#pragma unroll
    for (int ct = 0; ct < NTILES; ++ct) {
      unsigned short* Yw;
      int n;
      if constexpr (NTILES == 2) {
        Yw = (wv < 2) ? Y0 : Y1;
        n = (wv & 1) * 32 + ct * 16 + m;
      } else {
        Yw = Y0;
        n = wv * 16 + m;
      }
#pragma unroll
      for (int reg = 0; reg < 4; ++reg) {
        int row = row0 + rt * 16 + q * 4 + reg;
        if (row < N) Yw[(size_t)row * 64 + n] = f2bf(acc[rt][ct][reg]);
      }
    }
}

// ---------------------------------------------------------------------------
// MEGA1: decode+bucket-scatter + prep + WnL2T + layer-0 GEMM (WnT0 from
// k_flag). Proportional striping so decode co-resides with compute from t=0.
__global__ __launch_bounds__(256) void k_mega1(
    const unsigned int* __restrict__ w, const unsigned int* __restrict__ flag,
    int E, int nDec, int nWork, int gB,
    int* __restrict__ src, int* __restrict__ tgt,
    int* __restrict__ gcursor, unsigned int* __restrict__ tmp,
    const float* __restrict__ x, const unsigned short* __restrict__ WnT0,
    unsigned short* __restrict__ Yl,
    unsigned short* __restrict__ Yr, int N,
    const float* __restrict__ We2, const float* __restrict__ Wo1,
    const float* __restrict__ be2, const float* __restrict__ bo1,
    const float* __restrict__ We1,
    const float* __restrict__ Wl1, const float* __restrict__ Wr1,
    unsigned short* __restrict__ W25T, unsigned short* __restrict__ We1T,
    unsigned short* __restrict__ Wo1T, float* __restrict__ cvec,
    unsigned short* __restrict__ WnL2T) {
  __shared__ __align__(16) char smem[64 * 136 * 2];   // 17408 B, union use
  const int tid = threadIdx.x;
  const int tot = nDec + nWork;
  const int di  = (int)(((long long)blockIdx.x * nDec) / tot);
  const int di1 = (int)(((long long)(blockIdx.x + 1) * nDec) / tot);

  if (di1 > di) {
    // ---- decode+scatter block #di: edges [di*4096, min(E, +4096))
    int* hist = (int*)smem;   // 512 ints
    hist[tid] = 0; hist[tid + 256] = 0;
    __syncthreads();
    const int e0 = di * 4096;
    const int e1 = (e0 + 4096 < E) ? (e0 + 4096) : E;
    const unsigned int fl = flag[0];
    for (int e = e0 + tid; e < e1; e += 256) {
      int s, t;
      if (fl) { s = (int)w[e]; t = (int)w[E + e]; }
      else    { s = (int)w[2 * e]; t = (int)w[2 * (E + e)]; }
      src[e] = s; tgt[e] = t;
      atomicAdd(hist + (t >> 8), 1);
    }
    __syncthreads();
    {
      int c0 = hist[tid], c1 = hist[tid + 256];
      int s0 = (c0 > 0) ? atomicAdd(gcursor + tid, c0) : 0;
      int s1 = (c1 > 0) ? atomicAdd(gcursor + tid + 256, c1) : 0;
      __syncthreads();
      hist[tid] = s0; hist[tid + 256] = s1;
    }
    __syncthreads();
    for (int e = e0 + tid; e < e1; e += 256) {
      int s, t;
      if (fl) { s = (int)w[e]; t = (int)w[E + e]; }
      else    { s = (int)w[2 * e]; t = (int)w[2 * (E + e)]; }
      int b = t >> 8;
      int pos = atomicAdd(hist + b, 1);
      if (pos < CAPB)
        tmp[(size_t)b * CAPB + pos] = ((unsigned int)s << 8) | (unsigned int)(t & 255);
    }
    return;
  }
  const int wi = blockIdx.x - di;
  if (wi == 0) {
    // ---- prep: W25T=(We2@Wo1)^T, Wo1T, We1T, cvec (Wo1 staged in smem)
    float* sB = (float*)smem;
    for (int i = tid; i < 1024; i += 256)
      *(float4*)&sB[i * 4] = *(const float4*)(Wo1 + i * 4);
    __syncthreads();
    for (int idx = tid; idx < 4096; idx += 256) {
      int k = idx >> 6, n = idx & 63;   // k wave-uniform -> We2 scalarizes
      float s = 0.f;
#pragma unroll 8
      for (int mm = 0; mm < 64; ++mm) s = fmaf(We2[k * 64 + mm], sB[mm * 64 + n], s);
      W25T[n * 64 + k] = f2bf(s);
      Wo1T[n * 64 + k] = f2bf(sB[k * 64 + n]);
    }
    for (int idx = tid; idx < 2048; idx += 256) {
      int n = idx >> 5, k = idx & 31;
      We1T[n * 32 + k] = (k < 16) ? f2bf(We1[k * 64 + n]) : (unsigned short)0;
    }
    if (tid < 64) {
      float s = bo1[tid];
#pragma unroll 8
      for (int mm = 0; mm < 64; ++mm) s = fmaf(be2[mm], sB[mm * 64 + tid], s);
      cvec[tid] = s;
    }
  } else if (wi <= 32) {
    // ---- WnL2T: [64 n][128 k], k<64 from Wl1, k>=64 from Wr1 (stacked K)
    int idx = (wi - 1) * 256 + tid;   // 0..8191
    int n = idx >> 7, k = idx & 127;
    float v = (k < 64) ? Wl1[(size_t)k * 64 + n]
                       : Wr1[(size_t)(k - 64) * 64 + n];
    WnL2T[idx] = f2bf(v);
  } else {
    // ---- layer-0 GEMM (pre-transposed bf16 weights from k_flag)
    ngemm_body<128, false, 2>(x, WnT0, Yl, Yr, N, wi - 33,
                              (unsigned short*)smem);
  }
}

// ---------------------------------------------------------------------------
// Per-bucket counting sort + co-dispatched eattr conv (r8 form).
__global__ __launch_bounds__(256) void k_bsort(
    const unsigned int* __restrict__ tmp, const int* __restrict__ gcursor,
    int* __restrict__ csrc, uint2* __restrict__ rowptr2, int N, int nBuck,
    const float4* __restrict__ ef, uint2* __restrict__ eb, int nItems) {
  __shared__ int cnt[256];
  __shared__ int curs[256];
  __shared__ int wsum[4];
  const int tid = threadIdx.x;
  if (blockIdx.x >= nBuck) {
    const int ci = blockIdx.x - nBuck;
#pragma unroll
    for (int j = 0; j < 4; ++j) {
      int i = ci * 1024 + j * 256 + tid;
      if (i < nItems) {
        float4 v = ef[i];
        uint2 pk;
        pk.x = (unsigned int)f2bf(v.x) | ((unsigned int)f2bf(v.y) << 16);
        pk.y = (unsigned int)f2bf(v.z) | ((unsigned int)f2bf(v.w) << 16);
        eb[i] = pk;
      }
    }
    return;
  }
  const int b = blockIdx.x;
  int c = gcursor[b]; if (c > CAPB) c = CAPB;
  cnt[tid] = 0;
  __syncthreads();
  const unsigned int* reg = tmp + (size_t)b * CAPB;
  for (int i = tid; i < c; i += 256) atomicAdd(&cnt[reg[i] & 255u], 1);
  __syncthreads();
  const int lane = tid & 63, wv = tid >> 6;
  int v = cnt[tid];
  int incl = v;
#pragma unroll
  for (int off = 1; off < 64; off <<= 1) {
    int t = __shfl_up(incl, off, 64);
    if (lane >= off) incl += t;
  }
  if (lane == 63) wsum[wv] = incl;
  __syncthreads();
  int add = 0;
  for (int ww = 0; ww < wv; ++ww) add += wsum[ww];
  int excl = add + incl - v;
  curs[tid] = excl;
  int node = b * 256 + tid;
  if (node < N)
    rowptr2[node] = make_uint2((unsigned int)(b * CAPB + excl),
                               (unsigned int)(b * CAPB + excl + v));
  __syncthreads();
  for (int i = tid; i < c; i += 256) {
    unsigned int wd = reg[i];
    int p = atomicAdd(&curs[wd & 255u], 1);
    csrc[(size_t)b * CAPB + p] = (int)(wd >> 8);
  }
}

// ---------------------------------------------------------------------------
// CSR aggregate v3 (r11 proven): 8 edge-slots x 8 col-octs, uint4 loads.
// RAW=false: H = relu(sum/deg + bias + Yr). RAW=true: A = sum/deg.
template <bool RAW>
__global__ __launch_bounds__(256) void k_agg(
    const unsigned short* __restrict__ Y, const uint2* __restrict__ rowptr2,
    const int* __restrict__ csrc, const float* __restrict__ bias,
    const unsigned short* __restrict__ Yr, unsigned short* __restrict__ H,
    int N) {
  int node = (blockIdx.x * 256 + threadIdx.x) >> 6;
  if (node >= N) return;
  const int lane = threadIdx.x & 63;
  const int c8 = lane & 7;    // col-oct: cols [c8*8, c8*8+8)
  const int rr = lane >> 3;   // 8 edge slots
  uint2 be = rowptr2[node];
  int beg = (int)be.x, end = (int)be.y;
  float a0 = 0.f, a1 = 0.f, a2 = 0.f, a3 = 0.f;
  float a4 = 0.f, a5 = 0.f, a6 = 0.f, a7 = 0.f;
  float b0 = 0.f, b1 = 0.f, b2 = 0.f, b3 = 0.f;
  float b4 = 0.f, b5 = 0.f, b6 = 0.f, b7 = 0.f;
  for (int e = beg; e < end; e += 16) {
    int e0 = e + rr, e1 = e + 8 + rr;
    bool p0 = e0 < end, p1 = e1 < end;
    int s0 = p0 ? csrc[e0] : 0;
    int s1 = p1 ? csrc[e1] : 0;
    uint4 v0, v1;
    if (p0) v0 = *(const uint4*)(Y + (size_t)s0 * 64 + c8 * 8);
    if (p1) v1 = *(const uint4*)(Y + (size_t)s1 * 64 + c8 * 8);
    if (p0) {
      a0 += bf2f(v0.x & 0xffffu); a1 += bf2f(v0.x >> 16);
      a2 += bf2f(v0.y & 0xffffu); a3 += bf2f(v0.y >> 16);
      a4 += bf2f(v0.z & 0xffffu); a5 += bf2f(v0.z >> 16);
      a6 += bf2f(v0.w & 0xffffu); a7 += bf2f(v0.w >> 16);
    }
    if (p1) {
      b0 += bf2f(v1.x & 0xffffu); b1 += bf2f(v1.x >> 16);
      b2 += bf2f(v1.y & 0xffffu); b3 += bf2f(v1.y >> 16);
      b4 += bf2f(v1.z & 0xffffu); b5 += bf2f(v1.z >> 16);
      b6 += bf2f(v1.w & 0xffffu); b7 += bf2f(v1.w >> 16);
    }
  }
  a0 += b0; a1 += b1; a2 += b2; a3 += b3;
  a4 += b4; a5 += b5; a6 += b6; a7 += b7;
#pragma unroll
  for (int msk = 8; msk <= 32; msk <<= 1) {
    a0 += __shfl_xor(a0, msk, 64);
    a1 += __shfl_xor(a1, msk, 64);
    a2 += __shfl_xor(a2, msk, 64);
    a3 += __shfl_xor(a3, msk, 64);
    a4 += __shfl_xor(a4, msk, 64);
    a5 += __shfl_xor(a5, msk, 64);
    a6 += __shfl_xor(a6, msk, 64);
    a7 += __shfl_xor(a7, msk, 64);
  }
  if (rr == 0) {
    float cdeg = (float)(end - beg);
    if (cdeg < 1.f) cdeg = 1.f;
    float inv = 1.f / cdeg;
    float o0, o1, o2, o3, o4, o5, o6, o7;
    if constexpr (RAW) {
      o0 = a0 * inv; o1 = a1 * inv; o2 = a2 * inv; o3 = a3 * inv;
      o4 = a4 * inv; o5 = a5 * inv; o6 = a6 * inv; o7 = a7 * inv;
    } else {
      float4 bv0 = *(const float4*)(bias + c8 * 8);
      float4 bv1 = *(const float4*)(bias + c8 * 8 + 4);
      uint4 yv = *(const uint4*)(Yr + (size_t)node * 64 + c8 * 8);
      o0 = fmaxf(a0 * inv + bv0.x + bf2f(yv.x & 0xffffu), 0.f);
      o1 = fmaxf(a1 * inv + bv0.y + bf2f(yv.x >> 16), 0.f);
      o2 = fmaxf(a2 * inv + bv0.z + bf2f(yv.y & 0xffffu), 0.f);
      o3 = fmaxf(a3 * inv + bv0.w + bf2f(yv.y >> 16), 0.f);
      o4 = fmaxf(a4 * inv + bv1.x + bf2f(yv.z & 0xffffu), 0.f);
      o5 = fmaxf(a5 * inv + bv1.y + bf2f(yv.z >> 16), 0.f);
      o6 = fmaxf(a6 * inv + bv1.z + bf2f(yv.w & 0xffffu), 0.f);
      o7 = fmaxf(a7 * inv + bv1.w + bf2f(yv.w >> 16), 0.f);
    }
    uint4 pk;
    pk.x = (unsigned int)f2bf(o0) | ((unsigned int)f2bf(o1) << 16);
    pk.y = (unsigned int)f2bf(o2) | ((unsigned int)f2bf(o3) << 16);
    pk.z = (unsigned int)f2bf(o4) | ((unsigned int)f2bf(o5) << 16);
    pk.w = (unsigned int)f2bf(o6) | ((unsigned int)f2bf(o7) << 16);
    *(uint4*)(H + (size_t)node * 64 + c8 * 8) = pk;
  }
}

// ---------------------------------------------------------------------------
// FUSED layer-2 + G GEMM (r9 form): H2 = relu([A1|H] @ [Wl1;Wr1] + bl1) in
// registers (K=128 MFMA), LDS, then G = H2 @ Wo1 (K=64 MFMA).
__global__ __launch_bounds__(256) void k_gemm2g(
    const unsigned short* __restrict__ A1, const unsigned short* __restrict__ H,
    const float* __restrict__ bl1, const unsigned short* __restrict__ WnL2T,
    const unsigned short* __restrict__ Wo1T, unsigned short* __restrict__ Gb,
    int N) {
  __shared__ __align__(16) unsigned short sX[64 * 136];
  __shared__ __align__(16) unsigned short sH2[64 * 72];
  const int tid = threadIdx.x;
  const int wv = tid >> 6, lane = tid & 63;
  const int m = lane & 15, q = lane >> 4;
  const int row0 = blockIdx.x * 64;
  const int n = wv * 16 + m;

  short8 bB1[4], bB2[2];
#pragma unroll
  for (int c = 0; c < 4; ++c)
    bB1[c] = *(const short8*)(WnL2T + (size_t)n * 128 + c * 32 + q * 8);
#pragma unroll
  for (int c = 0; c < 2; ++c)
    bB2[c] = *(const short8*)(Wo1T + (size_t)n * 64 + c * 32 + q * 8);
  const float bl = bl1[n];

  // stage [A1|H]: 64 rows x 128 bf16 cols; cols 0-63 = A1, 64-127 = H
#pragma unroll
  for (int i = 0; i < 8; ++i) {
    int f = tid + 256 * i;        // 2048 uint2 quads
    int r = f >> 5;               // 32 quads per row
    int c4 = f & 31;
    int rr = row0 + r; if (rr >= N) rr = N - 1;
    uint2 pk;
    if (c4 < 16) pk = *(const uint2*)(A1 + (size_t)rr * 64 + c4 * 4);
    else         pk = *(const uint2*)(H  + (size_t)rr * 64 + (c4 - 16) * 4);
    *(uint2*)(sX + r * 136 + c4 * 4) = pk;
  }
  __syncthreads();

  // stage 1: K=128 MFMA -> H2
  f32x4 acc[4];
#pragma unroll
  for (int rt = 0; rt < 4; ++rt)
#pragma unroll
    for (int r = 0; r < 4; ++r) acc[rt][r] = 0.f;
#pragma unroll
  for (int c = 0; c < 4; ++c)
#pragma unroll
    for (int rt = 0; rt < 4; ++rt) {
      short8 a = *(const short8*)(sX + (rt * 16 + m) * 136 + c * 32 + q * 8);
      acc[rt] = __builtin_amdgcn_mfma_f32_16x16x32_bf16(a, bB1[c], acc[rt], 0, 0, 0);
    }

  // H2 = relu(acc + bl1) -> LDS (A-frag layout, stride 72)
#pragma unroll
  for (int rt = 0; rt < 4; ++rt)
#pragma unroll
    for (int reg = 0; reg < 4; ++reg)
      sH2[(rt * 16 + q * 4 + reg) * 72 + n] = f2bf(fmaxf(acc[rt][reg] + bl, 0.f));
  __syncthreads();

  // stage 2: K=64 MFMA -> G
  f32x4 acc2[4];
#pragma unroll
  for (int rt = 0; rt < 4; ++rt)
#pragma unroll
    for (int r = 0; r < 4; ++r) acc2[rt][r] = 0.f;
#pragma unroll
  for (int c = 0; c < 2; ++c)
#pragma unroll
    for (int rt = 0; rt < 4; ++rt) {
      short8 a = *(const short8*)(sH2 + (rt * 16 + m) * 72 + c * 32 + q * 8);
      acc2[rt] = __builtin_amdgcn_mfma_f32_16x16x32_bf16(a, bB2[c], acc2[rt], 0, 0, 0);
    }

#pragma unroll
  for (int rt = 0; rt < 4; ++rt)
#pragma unroll
    for (int reg = 0; reg < 4; ++reg) {
      int row = row0 + rt * 16 + q * 4 + reg;
      if (row < N) Gb[(size_t)row * 64 + n] = f2bf(acc2[rt][reg]);
    }
}

// ---------------------------------------------------------------------------
// MFMA edge pipeline v5 (r12 form): uint4 Gb gathers. Grid 1536 = exactly 6
// blocks/CU (LDS/VGPR residency limit) -> single fully-resident persistent
// round, no second dispatch round.
#define T1_STRIDE 72
#define G_STRIDE 68
__global__ __launch_bounds__(256) void k_edge3(
    const unsigned short* __restrict__ EAb, const int* __restrict__ src,
    const int* __restrict__ tgt, const unsigned short* __restrict__ Gb,
    const unsigned short* __restrict__ We1T,
    const unsigned short* __restrict__ W25T,
    const float* __restrict__ cvec, const float* __restrict__ be1,
    const float* __restrict__ Wo2, const float* __restrict__ bo2,
    float* __restrict__ out, int E, int nT, int nWaves) {
  __shared__ unsigned short sT1a[4][16 * T1_STRIDE];
  __shared__ float sGa[4][16 * G_STRIDE];
  const int tid = threadIdx.x;
  const int wid = tid >> 6, lane = tid & 63;
  const int m = lane & 15, q = lane >> 4;
  const int c8 = lane & 7, s8 = lane >> 3;
  unsigned short* sT1 = sT1a[wid];
  float* sG = sGa[wid];

  short8 bWe1[4], bW25[4][2];
  float cv[4], wo2v[4], be1v[4];
#pragma unroll
  for (int nt = 0; nt < 4; ++nt) {
    int n = nt * 16 + m;
    bWe1[nt] = *(const short8*)(We1T + n * 32 + q * 8);
    bW25[nt][0] = *(const short8*)(W25T + n * 64 + q * 8);
    bW25[nt][1] = *(const short8*)(W25T + n * 64 + 32 + q * 8);
    cv[nt] = cvec[n];
    wo2v[nt] = Wo2[n];
    be1v[nt] = be1[n];
  }
  const float b_out = bo2[0];
  const short8 zfrag = {};

  int t = blockIdx.x * 4 + wid;
  if (t >= nT) return;
  int il = t * 16 + m; if (il >= E) il = E - 1;
  int my_idx = (lane < 16) ? src[il] : ((lane < 32) ? tgt[il] : 0);

  while (true) {
    const int base = t * 16;
    const int tn = t + nWaves;
    const bool last = (tn >= nT);
    const int tc = last ? t : tn;

    int il_n = tc * 16 + m; if (il_n >= E) il_n = E - 1;
    int idx_n = (lane < 16) ? src[il_n] : ((lane < 32) ? tgt[il_n] : 0);

    // ---- Gb gathers: 2 edge-slots x {src,tgt}, uint4 per lane
    uint4 sv[2], tv[2];
#pragma unroll
    for (int j = 0; j < 2; ++j) {
      int es = s8 + 8 * j;
      int a = __shfl(my_idx, es, 64);
      int b = __shfl(my_idx, 16 + es, 64);
      sv[j] = *(const uint4*)(Gb + (size_t)a * 64 + c8 * 8);
      tv[j] = *(const uint4*)(Gb + (size_t)b * 64 + c8 * 8);
    }

    int er = base + m; if (er >= E) er = E - 1;
    short8 aEA = zfrag;
    if (q < 2) aEA = *(const short8*)(EAb + (size_t)er * 16 + (q & 1) * 8);

    f32x4 t1[4];
#pragma unroll
    for (int nt = 0; nt < 4; ++nt) {
      f32x4 cinit; cinit[0] = be1v[nt]; cinit[1] = be1v[nt];
      cinit[2] = be1v[nt]; cinit[3] = be1v[nt];
      t1[nt] = __builtin_amdgcn_mfma_f32_16x16x32_bf16(aEA, bWe1[nt], cinit, 0, 0, 0);
    }
#pragma unroll
    for (int nt = 0; nt < 4; ++nt)
#pragma unroll
      for (int r = 0; r < 4; ++r)
        sT1[(q * 4 + r) * T1_STRIDE + nt * 16 + m] = f2bf(fmaxf(t1[nt][r], 0.f));
    short8 aT0 = *(short8*)(sT1 + m * T1_STRIDE + q * 8);
    short8 aT1 = *(short8*)(sT1 + m * T1_STRIDE + 32 + q * 8);

    // ---- g = Gb[src]+Gb[tgt] -> sG (per-wave slice, wave-synchronous)
#pragma unroll
    for (int j = 0; j < 2; ++j) {
      int es = s8 + 8 * j;
      f32x4 g0, g1;
      g0[0] = bf2f(sv[j].x & 0xffffu) + bf2f(tv[j].x & 0xffffu);
      g0[1] = bf2f(sv[j].x >> 16)     + bf2f(tv[j].x >> 16);
      g0[2] = bf2f(sv[j].y & 0xffffu) + bf2f(tv[j].y & 0xffffu);
      g0[3] = bf2f(sv[j].y >> 16)     + bf2f(tv[j].y >> 16);
      g1[0] = bf2f(sv[j].z & 0xffffu) + bf2f(tv[j].z & 0xffffu);
      g1[1] = bf2f(sv[j].z >> 16)     + bf2f(tv[j].z >> 16);
      g1[2] = bf2f(sv[j].w & 0xffffu) + bf2f(tv[j].w & 0xffffu);
      g1[3] = bf2f(sv[j].w >> 16)     + bf2f(tv[j].w >> 16);
      *(f32x4*)(sG + es * G_STRIDE + c8 * 8) = g0;
      *(f32x4*)(sG + es * G_STRIDE + c8 * 8 + 4) = g1;
    }

    f32x4 acc[4];
#pragma unroll
    for (int nt = 0; nt < 4; ++nt)
#pragma unroll
      for (int r = 0; r < 4; ++r)
        acc[nt][r] = cv[nt] + sG[(q * 4 + r) * G_STRIDE + nt * 16 + m];
#pragma unroll
    for (int nt = 0; nt < 4; ++nt) {
      acc[nt] = __builtin_amdgcn_mfma_f32_16x16x32_bf16(aT0, bW25[nt][0], acc[nt], 0, 0, 0);
      acc[nt] = __builtin_amdgcn_mfma_f32_16x16x32_bf16(aT1, bW25[nt][1], acc[nt], 0, 0, 0);
    }

    float p[4];
#pragma unroll
    for (int r = 0; r < 4; ++r) {
      p[r] = fmaxf(acc[0][r], 0.f) * wo2v[0] + fmaxf(acc[1][r], 0.f) * wo2v[1] +
             fmaxf(acc[2][r], 0.f) * wo2v[2] + fmaxf(acc[3][r], 0.f) * wo2v[3];
    }
#pragma unroll
    for (int msk = 1; msk <= 8; msk <<= 1) {
#pragma unroll
      for (int r = 0; r < 4; ++r) p[r] += __shfl_xor(p[r], msk, 64);
    }
    if (m == 0) {
#pragma unroll
      for (int r = 0; r < 4; ++r) {
        int row = base + q * 4 + r;
        if (row < E) out[row] = 1.f / (1.f + __expf(-(p[r] + b_out)));
      }
    }

    if (last) break;
    t = tn; my_idx = idx_n;
  }
}

// ---------------------------------------------------------------------------
extern "C" void kernel_launch(void* const* d_in, const int* in_sizes, int n_in,
                              void* d_out, int out_size, void* d_ws, size_t ws_size,
                              hipStream_t stream) {
  const float* x     = (const float*)d_in[0];
  const unsigned int* eidx = (const unsigned int*)d_in[1];
  const float* eattr = (const float*)d_in[2];
  const float* We1 = (const float*)d_in[3];
  const float* be1 = (const float*)d_in[4];
  const float* We2 = (const float*)d_in[5];
  const float* be2 = (const float*)d_in[6];
  const float* Wl0 = (const float*)d_in[7];
  const float* bl0 = (const float*)d_in[8];
  const float* Wr0 = (const float*)d_in[9];
  const float* Wl1 = (const float*)d_in[10];
  const float* bl1 = (const float*)d_in[11];
  const float* Wr1 = (const float*)d_in[12];
  const float* Wo1 = (const float*)d_in[13];
  const float* bo1 = (const float*)d_in[14];
  const float* Wo2 = (const float*)d_in[15];
  const float* bo2 = (const float*)d_in[16];

  const int N = in_sizes[0] / 128;   // 100000
  const int E = in_sizes[2] / 16;    // 1000000
  const int NBUCK = (N + 255) >> 8;  // 391 coarse buckets (tgt>>8)
  float* out = (float*)d_out;

  char* ws = (char*)d_ws;
  size_t off = 0;
  auto alloc = [&](size_t bytes) {
    char* p = ws + off;
    off += (bytes + 255) & ~(size_t)255;
    return p;
  };
  unsigned int* flag = (unsigned int*)alloc(256);
  int* src    = (int*)alloc((size_t)E * 4);
  int* tgt    = (int*)alloc((size_t)E * 4);
  int* gcursor = (int*)alloc(512 * 4);
  unsigned int* tmp = (unsigned int*)alloc((size_t)NBUCK * CAPB * 4);
  int* csrc   = (int*)alloc((size_t)NBUCK * CAPB * 4);
  uint2* rowptr2 = (uint2*)alloc((size_t)N * 8);
  unsigned short* EAb = (unsigned short*)alloc((size_t)E * 16 * 2);
  unsigned short* Hb = (unsigned short*)alloc((size_t)N * 64 * 2);
  unsigned short* A1 = (unsigned short*)alloc((size_t)N * 64 * 2);
  unsigned short* Yl = (unsigned short*)alloc((size_t)N * 64 * 2);
  unsigned short* Yr = (unsigned short*)alloc((size_t)N * 64 * 2);
  unsigned short* Gb = (unsigned short*)alloc((size_t)N * 64 * 2);
  unsigned short* W25T = (unsigned short*)alloc(64 * 64 * 2);
  unsigned short* We1T = (unsigned short*)alloc(64 * 32 * 2);
  unsigned short* Wo1T = (unsigned short*)alloc(64 * 64 * 2);
  unsigned short* WnL2T = (unsigned short*)alloc(64 * 128 * 2);
  unsigned short* WnT0 = (unsigned short*)alloc(128 * 128 * 2);
  float* cvec = (float*)alloc(64 * 4);
  (void)ws_size; (void)n_in; (void)out_size;

  // flag + gcursor zero + WnT0 transpose (64 blocks)
  k_flag<<<66, 256, 0, stream>>>(eidx, 8192, flag, gcursor, Wl0, Wr0, WnT0);

  // MEGA1: decode+scatter + prep + WnL2T + layer-0 GEMM
  const int nDec = (E + 4095) / 4096;   // 245 decode+scatter blocks
  const int gB = (N + 63) / 64;
  const int nWork = 33 + gB;
  k_mega1<<<nDec + nWork, 256, 0, stream>>>(
      eidx, flag, E, nDec, nWork, gB,
      src, tgt, gcursor, tmp,
      x, WnT0, Yl, Yr, N,
      We2, Wo1, be2, bo1, We1, Wl1, Wr1,
      W25T, We1T, Wo1T, cvec, WnL2T);

  // bsort (391 long-pole blocks first) + co-dispatched eattr conv
  const int nConv = (E * 4 + 1023) / 1024;   // 3907 conv blocks
  k_bsort<<<NBUCK + nConv, 256, 0, stream>>>(tmp, gcursor, csrc, rowptr2, N,
                                             NBUCK, (const float4*)eattr,
                                             (uint2*)EAb, E * 4);

  const int aggB = (N + 3) / 4;
  // agg0: H = relu(mean(Yl[src]) + bl0 + Yr)
  k_agg<false><<<aggB, 256, 0, stream>>>(Yl, rowptr2, csrc, bl0, Yr, Hb, N);
  // agg1': A1 = mean(H[src])  (raw mean; linearity moves Wl1 after the agg)
  k_agg<true><<<aggB, 256, 0, stream>>>(Hb, rowptr2, csrc, nullptr, nullptr,
                                        A1, N);
  // fused layer-2 + G: H2 = relu([A1|H]@[Wl1;Wr1]+bl1); G = H2@Wo1
  k_gemm2g<<<gB, 256, 0, stream>>>(A1, Hb, bl1, WnL2T, Wo1T, Gb, N);

  // MFMA edge pipeline v5: fully-resident persistent grid
  const int nT = (E + 15) / 16;
  const int blocks = 1536;
  k_edge3<<<blocks, 256, 0, stream>>>(EAb, src, tgt, Gb, We1T, W25T, cvec,
                                      be1, Wo2, bo2, out, E, nT, blocks * 4);
}